// Round 9
// baseline (397.697 us; speedup 1.0000x reference)
//
#include <hip/hip_runtime.h>
#include <stdint.h>

// Problem constants
#define B_   16
#define N_   4096
#define M_   1024
#define NT   (B_*M_*32)      // 524288 samples
#define BM   (B_*M_)         // 16384 (b,m) groups
#define REP  64              // stats-accumulator replicas (atomic decontention)

typedef unsigned short u16;
typedef unsigned long long u64;
typedef __attribute__((ext_vector_type(8))) short short8;   // 8 bf16 (4 VGPRs)
typedef __attribute__((ext_vector_type(4))) float f32x4;    // MFMA C/D

union FragU { uint4 u; short8 s; };

__device__ __forceinline__ float bf2f(u16 u){
    return __uint_as_float(((unsigned int)u) << 16);
}
__device__ __forceinline__ u16 f2bf(float f){
    unsigned int u = __float_as_uint(f);
    return (u16)((u + 0x7FFFu + ((u >> 16) & 1u)) >> 16);
}

// ---------------------------------------------------------------------------
// features [B][64][N] f32 -> featT [B][N][64] f32
// ---------------------------------------------------------------------------
__global__ __launch_bounds__(256) void k_feat(const float* __restrict__ feat,
                                              float* __restrict__ featT){
    __shared__ float tile[64][65];
    int b  = blockIdx.y;
    int n0 = blockIdx.x * 64;
    for (int t = threadIdx.x; t < 4096; t += 256){
        int c = t >> 6, n = t & 63;
        tile[c][n] = feat[((size_t)(b*64 + c))*N_ + n0 + n];
    }
    __syncthreads();
    for (int t = threadIdx.x; t < 4096; t += 256){
        int n = t >> 6, c = t & 63;
        featT[((size_t)(b*N_) + n0 + n)*64 + c] = tile[c][n];
    }
}

// ---------------------------------------------------------------------------
// pack loc -> (x,y,z,x2)
// ---------------------------------------------------------------------------
__global__ __launch_bounds__(256) void k_prep(const float* __restrict__ locF,
                                              float4* __restrict__ locP){
    int i = blockIdx.x*256 + threadIdx.x;   // B_*N_ = 65536 points
    float lx = locF[(size_t)i*3+0], ly = locF[(size_t)i*3+1], lz = locF[(size_t)i*3+2];
    float x2 = __fadd_rn(__fadd_rn(__fmul_rn(lx,lx), __fmul_rn(ly,ly)), __fmul_rn(lz,lz));
    locP[i] = make_float4(lx, ly, lz, x2);
}

// ---------------------------------------------------------------------------
// exact KNN (32 smallest of 4096), r9: WAVE-AUTONOMOUS value-domain bucket
// select. r8's version ran all 4 waves in lockstep: 2 __syncthreads + 2
// cross-wave LDS rounds per level -> Occ 51%, VALUBusy 72% (25% issue-idle).
// Now each wave owns points [wv*1024, +1024) and selects its exact local
// top-32 independently (own hist region, butterfly-only min/max, NO block
// barriers in the level loop; in-wave LDS ordering via in-order lgkmcnt).
// One barrier, then 128->32 merge by (key,idx) u64 rank — global top-32 is
// a subset of the union of per-wave top-32s, ranking order identical to r8,
// so the selection SET is unchanged. Value-domain bucketing retained (r7
// ERRATA: raw-bit radix collapses buckets -> 7x LDS conflicts; don't).
// ---------------------------------------------------------------------------
__global__ __launch_bounds__(256) void k_knn(const float4* __restrict__ locP,
                                             const float* __restrict__ nlocF,
                                             int* __restrict__ idxOut){
    const int tid  = threadIdx.x;
    const int lane = tid & 63, wv = tid >> 6;
    const int q    = blockIdx.x;
    const int b    = q >> 10, m = q & 1023;

    __shared__ unsigned int hist[4][256];   // per-wave histograms
    __shared__ u64 wOut[4][32];             // per-wave exact top-32 (key,idx)
    __shared__ u64 wCand[4][128];           // per-wave boundary candidates
    __shared__ int wCnt[4], wCandN[4];

    if (lane == 0){ wCnt[wv] = 0; wCandN[wv] = 0; }

    float qx = nlocF[(size_t)(b*M_ + m)*3 + 0];
    float qy = nlocF[(size_t)(b*M_ + m)*3 + 1];
    float qz = nlocF[(size_t)(b*M_ + m)*3 + 2];
    float y2 = __fadd_rn(__fadd_rn(__fmul_rn(qx,qx), __fmul_rn(qy,qy)), __fmul_rn(qz,qz));

    // wave wv owns points wv*1024 + i*64 + lane
    unsigned int key[16];
    const float4* lb = locP + (size_t)b*N_ + (size_t)wv*1024;
    #pragma unroll
    for (int i = 0; i < 16; ++i){
        float4 p = lb[i*64 + lane];
        float dt = __fadd_rn(__fadd_rn(__fmul_rn(qx,p.x), __fmul_rn(qy,p.y)), __fmul_rn(qz,p.z));
        float d2 = __fsub_rn(__fadd_rn(y2, p.w), __fmul_rn(2.0f, dt));
        d2 = fmaxf(d2, 0.0f);
        key[i] = __float_as_uint(d2);
    }

    // wave-local min/max (butterfly only — no LDS rounds)
    float lo = 3.4e38f, hi = 0.0f;
    #pragma unroll
    for (int i = 0; i < 16; ++i){
        float kf = __uint_as_float(key[i]);
        lo = fminf(lo, kf); hi = fmaxf(hi, kf);
    }
    #pragma unroll
    for (int st = 1; st < 64; st <<= 1){
        lo = fminf(lo, __shfl_xor(lo, st, 64));
        hi = fmaxf(hi, __shfl_xor(hi, st, 64));
    }

    unsigned int act = 0xFFFFu;
    int bkt[16];
    int R = 32;

    for (int lvl = 0; lvl < 8; ++lvl){
        float scale = 255.0f / fmaxf(hi - lo, 1e-35f);
        *(uint4*)&hist[wv][lane << 2] = make_uint4(0,0,0,0);
        #pragma unroll
        for (int i = 0; i < 16; ++i){
            if (act & (1u << i)){
                float kf = __uint_as_float(key[i]);
                int bb = (int)((kf - lo) * scale);
                bb = bb < 0 ? 0 : (bb > 255 ? 255 : bb);
                bkt[i] = bb;
                atomicAdd(&hist[wv][bb], 1u);
            }
        }
        uint4 h = *(const uint4*)&hist[wv][lane << 2];
        int tot = (int)(h.x + h.y + h.z + h.w);
        int v = tot;
        #pragma unroll
        for (int st = 1; st < 64; st <<= 1){
            int u = __shfl_up(v, st, 64);
            if (lane >= st) v += u;
        }
        u64 bal = __ballot(v >= R);
        int Ls = __ffsll((unsigned long long)bal) - 1;
        int exclS = __shfl(v - tot, Ls, 64);
        int hx = __shfl((int)h.x, Ls, 64), hy = __shfl((int)h.y, Ls, 64);
        int hz = __shfl((int)h.z, Ls, 64), hw = __shfl((int)h.w, Ls, 64);
        int c0 = exclS + hx, c1 = c0 + hy, c2 = c1 + hz;
        int jj    = (c0 >= R) ? 0 : (c1 >= R) ? 1 : (c2 >= R) ? 2 : 3;
        int below = (jj == 0) ? exclS : (jj == 1) ? c0 : (jj == 2) ? c1 : c2;
        int cnt   = (jj == 0) ? hx : (jj == 1) ? hy : (jj == 2) ? hz : hw;
        int qb = Ls*4 + jj;
        R -= below;
        bool brk = (cnt <= 128) || (lvl == 7);

        float nlo = 3.4e38f, nhi = 0.0f;
        #pragma unroll
        for (int i = 0; i < 16; ++i){
            if (act & (1u << i)){
                int bb = bkt[i];
                if (bb < qb){
                    int pos = atomicAdd(&wCnt[wv], 1);
                    if (pos < 32)
                        wOut[wv][pos] = (((u64)key[i]) << 32) | (unsigned int)(wv*1024 + i*64 + lane);
                    act &= ~(1u << i);
                } else if (bb > qb){
                    act &= ~(1u << i);
                } else if (!brk){
                    float kf = __uint_as_float(key[i]);
                    nlo = fminf(nlo, kf); nhi = fmaxf(nhi, kf);
                }
            }
        }
        if (brk) break;
        #pragma unroll
        for (int st = 1; st < 64; st <<= 1){
            nlo = fminf(nlo, __shfl_xor(nlo, st, 64));
            nhi = fmaxf(nhi, __shfl_xor(nhi, st, 64));
        }
        lo = nlo; hi = nhi;
    }

    // boundary candidates -> per-wave buffer
    #pragma unroll
    for (int i = 0; i < 16; ++i){
        if (act & (1u << i)){
            int pos = atomicAdd(&wCandN[wv], 1);
            if (pos < 128)
                wCand[wv][pos] = (((u64)key[i]) << 32) | (unsigned int)(wv*1024 + i*64 + lane);
        }
    }
    // per-wave rank of candidates fills wOut[wv][base..31] (exactly R slots)
    {
        int cW   = wCandN[wv]; cW = cW < 128 ? cW : 128;
        int base = wCnt[wv];   base = base < 32 ? base : 32;
        for (int e = lane; e < cW; e += 64){
            u64 me = wCand[wv][e];
            int rank = 0;
            for (int j = 0; j < cW; ++j) rank += (wCand[wv][j] < me) ? 1 : 0;
            if (rank < R) wOut[wv][base + rank] = me;
        }
    }
    __syncthreads();
    // merge: global top-32 of the 4x32 per-wave winners, by (key,idx)
    if (tid < 128){
        u64 me = ((const u64*)wOut)[tid];
        int rank = 0;
        #pragma unroll 4
        for (int j = 0; j < 128; ++j) rank += (((const u64*)wOut)[j] < me) ? 1 : 0;
        if (rank < 32) idxOut[(size_t)q*32 + rank] = (int)(me & 0xFFFFFFFFull);
    }
}

// ---------------------------------------------------------------------------
// conv1 via MFMA, direct-to-register A gather; stats via replicated atomics.
// ---------------------------------------------------------------------------
__global__ __launch_bounds__(256) void k_conv1m(const int* __restrict__ idx,
                                                const float* __restrict__ locF,
                                                const float* __restrict__ nlocF,
                                                const float* __restrict__ featT,
                                                const float* __restrict__ W1,
                                                u16* __restrict__ y1,
                                                float* __restrict__ gsum,
                                                float* __restrict__ gsq){
    __shared__ uint4 bfB[4*5*64];   // 20 KB: frag (nt,kk) at (nt*5+kk)*64 + lane
    __shared__ u16  tileT[64*136];  // 17 KB transpose-out, stride 136 u16 = 272 B
    __shared__ float sSum[64], sSq[64];
    const int t   = threadIdx.x;
    const int bid = blockIdx.x;
    const int rep = bid & (REP-1);
    const int swz = (bid & 7)*512 + (bid >> 3);   // XCD-contiguous chunks
    const int s0  = swz * 128;
    const int b   = s0 >> 15;

    if (t < 64){ sSum[t] = 0.0f; sSq[t] = 0.0f; }

    // stage B': W1 hi duplicated in both halves of each k'-pair word
    #pragma unroll
    for (int rp = 0; rp < 5; ++rp){
        int cid = rp*256 + t;             // = (nt*5+kk)*64 + ln, cid < 1280
        int ln  = cid & 63;
        int kk  = (cid >> 6) % 5;
        int nt  = cid / 320;
        int o   = nt*16 + (ln & 15);
        int qq  = ln >> 4;
        int cb  = kk*16 + qq*4;           // phys channel base of this uint4
        unsigned int d[4];
        #pragma unroll
        for (int h = 0; h < 4; ++h){
            int c = cb + h;
            float wv = (c < 64) ? W1[o*67 + 3 + c] : ((c < 67) ? W1[o*67 + (c - 64)] : 0.0f);
            unsigned int wh = (unsigned int)f2bf(wv);
            d[h] = wh | (wh << 16);
        }
        bfB[cid] = make_uint4(d[0], d[1], d[2], d[3]);
    }

    // direct A gather: wave w -> m-tiles 2w,2w+1; lane q=l>>4 selects k-quad
    const int w = t >> 6, lane = t & 63;
    const int m15 = lane & 15, q = lane >> 4;

    int nrow[2], sg[2];
    float4 fa[2][4];
    #pragma unroll
    for (int mt = 0; mt < 2; ++mt){
        int sl = (2*w + mt)*16 + m15;
        sg[mt] = s0 + sl;
        int n = idx[sg[mt]]; if ((unsigned)n >= N_) n = 0;
        nrow[mt] = n;
        const float4* fp = (const float4*)&featT[((size_t)(b*N_) + n)*64];
        #pragma unroll
        for (int kq = 0; kq < 4; ++kq)
            fa[mt][kq] = fp[kq*4 + q];     // phys cols kq*16+q*4 .. +3
    }
    // xyz fragment (kk=4): only q==0 lanes carry data (phys c 64..67)
    uint4 axyz[2];
    axyz[0] = make_uint4(0,0,0,0); axyz[1] = make_uint4(0,0,0,0);
    if (q == 0){
        #pragma unroll
        for (int mt = 0; mt < 2; ++mt){
            int n = nrow[mt];
            int m = (sg[mt] >> 5) & 1023;
            const float* lp = &locF[(size_t)(b*N_ + n)*3];
            const float* qp = &nlocF[(size_t)(b*M_ + m)*3];
            unsigned int dd[3];
            #pragma unroll
            for (int e = 0; e < 3; ++e){
                float r  = lp[e] - qp[e];
                u16 hi   = f2bf(r);
                float lo = r - bf2f(hi);
                dd[e] = (unsigned int)hi | (((unsigned int)f2bf(lo)) << 16);
            }
            axyz[mt] = make_uint4(dd[0], dd[1], dd[2], 0u);
        }
    }
    __syncthreads();   // bfB ready (also covers sSum init)

    f32x4 acc[2][4];
    #pragma unroll
    for (int mt = 0; mt < 2; ++mt)
        #pragma unroll
        for (int nt = 0; nt < 4; ++nt)
            acc[mt][nt] = (f32x4){0.0f, 0.0f, 0.0f, 0.0f};

    #pragma unroll
    for (int kk = 0; kk < 5; ++kk){
        FragU af[2];
        #pragma unroll
        for (int mt = 0; mt < 2; ++mt){
            if (kk < 4){
                float4 f = fa[mt][kk];
                float fv[4] = {f.x, f.y, f.z, f.w};
                unsigned int d[4];
                #pragma unroll
                for (int e = 0; e < 4; ++e){
                    u16 hi   = f2bf(fv[e]);
                    float lo = fv[e] - bf2f(hi);
                    d[e] = (unsigned int)hi | (((unsigned int)f2bf(lo)) << 16);
                }
                af[mt].u = make_uint4(d[0], d[1], d[2], d[3]);
            } else {
                af[mt].u = axyz[mt];
            }
        }
        #pragma unroll
        for (int nt = 0; nt < 4; ++nt){
            FragU bu; bu.u = bfB[(nt*5 + kk)*64 + lane];
            #pragma unroll
            for (int mt = 0; mt < 2; ++mt)
                acc[mt][nt] = __builtin_amdgcn_mfma_f32_16x16x32_bf16(af[mt].s, bu.s, acc[mt][nt], 0, 0, 0);
        }
    }

    // fused stats: channel o = nt*16 + (lane&15); butterfly strides 16,32
    {
        float st4[4], sq4[4];
        #pragma unroll
        for (int nt = 0; nt < 4; ++nt){ st4[nt] = 0.0f; sq4[nt] = 0.0f; }
        #pragma unroll
        for (int mt = 0; mt < 2; ++mt)
            #pragma unroll
            for (int nt = 0; nt < 4; ++nt){
                f32x4 a = acc[mt][nt];
                st4[nt] += (a[0] + a[1]) + (a[2] + a[3]);
                float qv = a[0]*a[0];
                qv = fmaf(a[1], a[1], qv); qv = fmaf(a[2], a[2], qv); qv = fmaf(a[3], a[3], qv);
                sq4[nt] += qv;
            }
        #pragma unroll
        for (int st = 16; st < 64; st <<= 1){
            #pragma unroll
            for (int nt = 0; nt < 4; ++nt){
                st4[nt] += __shfl_xor(st4[nt], st, 64);
                sq4[nt] += __shfl_xor(sq4[nt], st, 64);
            }
        }
        if (lane < 16){
            #pragma unroll
            for (int nt = 0; nt < 4; ++nt){
                atomicAdd(&sSum[nt*16 + lane], st4[nt]);
                atomicAdd(&sSq[nt*16 + lane],  sq4[nt]);
            }
        }
    }

    // transpose D -> channel-major bf16 via padded LDS tile
    #pragma unroll
    for (int mt = 0; mt < 2; ++mt){
        int s_base = w*32 + mt*16 + (lane >> 4)*4;
        #pragma unroll
        for (int nt = 0; nt < 4; ++nt){
            int o = nt*16 + (lane & 15);
            f32x4 a = acc[mt][nt];
            unsigned int p01 = (unsigned int)f2bf(a[0]) | (((unsigned int)f2bf(a[1])) << 16);
            unsigned int p23 = (unsigned int)f2bf(a[2]) | (((unsigned int)f2bf(a[3])) << 16);
            *(unsigned int*)&tileT[o*136 + s_base]     = p01;
            *(unsigned int*)&tileT[o*136 + s_base + 2] = p23;
        }
    }
    __syncthreads();

    // coalesced channel-major store: thread t -> channel c=t>>2, 32-sample chunk
    {
        int c  = t >> 2;
        int g0 = (t & 3)*32;
        #pragma unroll
        for (int j = 0; j < 4; ++j){
            uint4 v = *(const uint4*)&tileT[c*136 + g0 + j*8];
            *(uint4*)&y1[(size_t)c*NT + s0 + g0 + j*8] = v;
        }
    }
    if (t < 64){
        atomicAdd(&gsum[rep*64 + t], sSum[t]);
        atomicAdd(&gsq[rep*64 + t],  sSq[t]);
    }
}

// ---------------------------------------------------------------------------
// conv2 via MFMA (verified): A = affine+relu(y1) frags (XOR-swizzled LDS),
// B = W2 frags; transpose-out via padded LDS; fused per-channel stats
// (replicated atomics, r5).
// ---------------------------------------------------------------------------
__global__ __launch_bounds__(256) void k_conv2m(const u16* __restrict__ yin,
                                                const float* __restrict__ W2,
                                                const float* __restrict__ prm,
                                                u16* __restrict__ yout,
                                                float* __restrict__ gsum,
                                                float* __restrict__ gsq){
    __shared__ uint4 bfA[2048];     // act frags: (mtg*2+kk)*64 + (l64 ^ (mtg&7)) (32 KB)
    __shared__ uint4 bfB[512];      // W2 frags:  (nt*2+kk)*64 + lane             (8 KB)
    __shared__ u16  tileT[64*264];  // transpose-out, stride 264 u16 = 528 B     (33 KB)
    __shared__ float sS[64], sT[64];
    __shared__ float sSum[64], sSq[64];
    const int t   = threadIdx.x;
    const int rep = blockIdx.x & (REP-1);
    const int s0  = blockIdx.x * 256;

    if (t < 64){ sS[t] = prm[t]; sT[t] = prm[64 + t]; sSum[t] = 0.0f; sSq[t] = 0.0f; }
    __syncthreads();

    // stage B: W2 [64][64] f32 -> bf16 frags (n=o within tile), nt in [0,4)
    #pragma unroll
    for (int rp = 0; rp < 2; ++rp){
        int cid = rp*256 + t;
        int ln  = cid & 63;
        int kk  = (cid >> 6) & 1;
        int nt  = cid >> 7;
        int o   = nt*16 + (ln & 15);
        int k0  = kk*32 + (ln >> 4)*8;
        const float* wp = &W2[o*64 + k0];
        unsigned int d[4];
        #pragma unroll
        for (int h = 0; h < 4; ++h)
            d[h] = (unsigned int)f2bf(wp[2*h]) | (((unsigned int)f2bf(wp[2*h+1])) << 16);
        bfB[cid] = make_uint4(d[0], d[1], d[2], d[3]);
    }

    // stage A: y1 channel-major; affine+relu; m=sample frags, XOR-swizzled
    {
        int oct = t >> 5;            // channels oct*8..+7: kk=oct>>2, qd=oct&3
        int sg  = t & 31;            // samples sg*8..+7 (local)
        int c0  = oct*8;
        int kk  = oct >> 2;
        int qd  = oct & 3;
        u16 rb[8][8];                // [j (=c-c0)][i (=sample)] — constant-indexed only
        #pragma unroll
        for (int j = 0; j < 8; ++j){
            int c = c0 + j;
            uint4 pk = *(const uint4*)&yin[(size_t)c*NT + s0 + sg*8];
            float sc = sS[c], tb = sT[c];
            unsigned int w4[4] = {pk.x, pk.y, pk.z, pk.w};
            #pragma unroll
            for (int h = 0; h < 4; ++h){
                rb[j][2*h]   = f2bf(fmaxf(fmaf(bf2f((u16)(w4[h] & 0xFFFF)), sc, tb), 0.0f));
                rb[j][2*h+1] = f2bf(fmaxf(fmaf(bf2f((u16)(w4[h] >> 16)),   sc, tb), 0.0f));
            }
        }
        #pragma unroll
        for (int i = 0; i < 8; ++i){            // i is a literal after unroll
            int s   = sg*8 + i;
            int mtg = s >> 4, m15 = s & 15;
            int l64 = qd*16 + m15;
            int cb  = (mtg*2 + kk)*64 + (l64 ^ (mtg & 7));   // XOR swizzle
            unsigned int d[4];
            #pragma unroll
            for (int h = 0; h < 4; ++h)
                d[h] = (unsigned int)rb[2*h][i] | (((unsigned int)rb[2*h+1][i]) << 16);
            bfA[cb] = make_uint4(d[0], d[1], d[2], d[3]);
        }
    }
    __syncthreads();

    // MFMA: wave w -> m-tiles 4w..4w+3 (samples w*64..+63), 4 n-tiles (64 ch)
    const int w = t >> 6, lane = t & 63;
    f32x4 acc[4][4];
    #pragma unroll
    for (int mt = 0; mt < 4; ++mt)
        #pragma unroll
        for (int nt = 0; nt < 4; ++nt)
            acc[mt][nt] = (f32x4){0.0f, 0.0f, 0.0f, 0.0f};

    #pragma unroll
    for (int kk = 0; kk < 2; ++kk){
        short8 af[4];
        #pragma unroll
        for (int mt = 0; mt < 4; ++mt){
            int tile = 4*w + mt;
            af[mt] = *((const short8*)&bfA[(tile*2 + kk)*64 + (lane ^ (tile & 7))]);
        }
        #pragma unroll
        for (int nt = 0; nt < 4; ++nt){
            short8 bfr = *((const short8*)&bfB[(nt*2 + kk)*64 + lane]);
            #pragma unroll
            for (int mt = 0; mt < 4; ++mt)
                acc[mt][nt] = __builtin_amdgcn_mfma_f32_16x16x32_bf16(af[mt], bfr, acc[mt][nt], 0, 0, 0);
        }
    }

    // fused stats: channel o = nt*16 + (lane&15); butterfly strides 16,32
    {
        float st4[4], sq4[4];
        #pragma unroll
        for (int nt = 0; nt < 4; ++nt){ st4[nt] = 0.0f; sq4[nt] = 0.0f; }
        #pragma unroll
        for (int mt = 0; mt < 4; ++mt)
            #pragma unroll
            for (int nt = 0; nt < 4; ++nt){
                f32x4 a = acc[mt][nt];
                st4[nt] += (a[0] + a[1]) + (a[2] + a[3]);
                float qq = a[0]*a[0];
                qq = fmaf(a[1], a[1], qq); qq = fmaf(a[2], a[2], qq); qq = fmaf(a[3], a[3], qq);
                sq4[nt] += qq;
            }
        #pragma unroll
        for (int st = 16; st < 64; st <<= 1){
            #pragma unroll
            for (int nt = 0; nt < 4; ++nt){
                st4[nt] += __shfl_xor(st4[nt], st, 64);
                sq4[nt] += __shfl_xor(sq4[nt], st, 64);
            }
        }
        if (lane < 16){
            #pragma unroll
            for (int nt = 0; nt < 4; ++nt){
                atomicAdd(&sSum[nt*16 + lane], st4[nt]);
                atomicAdd(&sSq[nt*16 + lane],  sq4[nt]);
            }
        }
    }

    // transpose D -> channel-major bf16 via padded LDS tile
    #pragma unroll
    for (int mt = 0; mt < 4; ++mt){
        int s_base = w*64 + mt*16 + (lane >> 4)*4;
        #pragma unroll
        for (int nt = 0; nt < 4; ++nt){
            int o = nt*16 + (lane & 15);
            f32x4 a = acc[mt][nt];
            unsigned int p01 = (unsigned int)f2bf(a[0]) | (((unsigned int)f2bf(a[1])) << 16);
            unsigned int p23 = (unsigned int)f2bf(a[2]) | (((unsigned int)f2bf(a[3])) << 16);
            *(unsigned int*)&tileT[o*264 + s_base]     = p01;
            *(unsigned int*)&tileT[o*264 + s_base + 2] = p23;
        }
    }
    __syncthreads();

    // coalesced channel-major store: thread t -> row c=t>>2, 8x16B chunks
    {
        int c  = t >> 2;
        int g0 = (t & 3)*8;
        #pragma unroll
        for (int j = 0; j < 8; ++j){
            uint4 v = *(const uint4*)&tileT[c*264 + (g0 + j)*8];
            *(uint4*)&yout[(size_t)c*NT + s0 + (g0 + j)*8] = v;
        }
    }
    if (t < 64){
        atomicAdd(&gsum[rep*64 + t], sSum[t]);
        atomicAdd(&gsq[rep*64 + t],  sSq[t]);
    }
}

// ---------------------------------------------------------------------------
// conv3 via MFMA: A = activations (m=sample), B = W3 (n=channel) -> D row =
// sample. Epilogue: in-reg reduce + cross-quad butterfly; gmax/gmin
// [group][o] coalesced; stats via replicated atomics (r5).
// ---------------------------------------------------------------------------
__global__ __launch_bounds__(256) void k_conv3m(const u16* __restrict__ yin,
                                                const float* __restrict__ W3,
                                                const float* __restrict__ prm,
                                                float* __restrict__ gsum, float* __restrict__ gsq,
                                                float* __restrict__ gmax, float* __restrict__ gmin){
    __shared__ uint4 bfA[2048];     // act frags: (mtg*2+kk)*64 + (lane64 ^ (mtg&7))  (32 KB)
    __shared__ uint4 bfB[1024];     // W3 frags:  (nt*2+kk)*64 + lane                 (16 KB)
    __shared__ float sS[64], sT[64];
    __shared__ float sSum[128], sSq[128];
    const int t   = threadIdx.x;
    const int rep = blockIdx.x & (REP-1);
    const int s0  = blockIdx.x * 256;

    if (t < 64){ sS[t] = prm[t]; sT[t] = prm[64 + t]; }
    if (t < 128){ sSum[t] = 0.0f; sSq[t] = 0.0f; }
    __syncthreads();

    // stage B: W3 [128][64] f32 -> bf16 frags (n=channel within tile)
    #pragma unroll
    for (int rp = 0; rp < 4; ++rp){
        int cid = rp*256 + t;
        int ln  = cid & 63;
        int kk  = (cid >> 6) & 1;
        int nt  = cid >> 7;
        int o   = nt*16 + (ln & 15);
        int k0  = kk*32 + (ln >> 4)*8;
        const float* wp = &W3[o*64 + k0];
        unsigned int d[4];
        #pragma unroll
        for (int h = 0; h < 4; ++h)
            d[h] = (unsigned int)f2bf(wp[2*h]) | (((unsigned int)f2bf(wp[2*h+1])) << 16);
        bfB[cid] = make_uint4(d[0], d[1], d[2], d[3]);
    }

    // stage A: y2 channel-major; affine+relu; m=sample frags, XOR-swizzled
    {
        int oct = t >> 5;            // channels oct*8..+7: kk=oct>>2, qd=oct&3
        int sg  = t & 31;            // samples sg*8..+7 (local)
        int c0  = oct*8;
        int kk  = oct >> 2;
        int qd  = oct & 3;
        u16 rb[8][8];                // [j (=c-c0)][i (=sample)] — constant-indexed only
        #pragma unroll
        for (int j = 0; j < 8; ++j){
            int c = c0 + j;
            uint4 pk = *(const uint4*)&yin[(size_t)c*NT + s0 + sg*8];
            float sc = sS[c], tb = sT[c];
            unsigned int w4[4] = {pk.x, pk.y, pk.z, pk.w};
            #pragma unroll
            for (int h = 0; h < 4; ++h){
                rb[j][2*h]   = f2bf(fmaxf(fmaf(bf2f((u16)(w4[h] & 0xFFFF)), sc, tb), 0.0f));
                rb[j][2*h+1] = f2bf(fmaxf(fmaf(bf2f((u16)(w4[h] >> 16)),   sc, tb), 0.0f));
            }
        }
        #pragma unroll
        for (int i = 0; i < 8; ++i){            // i is a literal after unroll
            int s   = sg*8 + i;
            int mtg = s >> 4, m15 = s & 15;
            int l64 = qd*16 + m15;
            int cb  = (mtg*2 + kk)*64 + (l64 ^ (mtg & 7));   // XOR swizzle
            unsigned int d[4];
            #pragma unroll
            for (int h = 0; h < 4; ++h)
                d[h] = (unsigned int)rb[2*h][i] | (((unsigned int)rb[2*h+1][i]) << 16);
            bfA[cb] = make_uint4(d[0], d[1], d[2], d[3]);
        }
    }
    __syncthreads();

    // MFMA: wave w -> m-tiles 4w..4w+3 (samples w*64..+63), all 8 n-tiles
    const int w = t >> 6, lane = t & 63;
    f32x4 acc[4][8];
    #pragma unroll
    for (int mt = 0; mt < 4; ++mt)
        #pragma unroll
        for (int nt = 0; nt < 8; ++nt)
            acc[mt][nt] = (f32x4){0.0f, 0.0f, 0.0f, 0.0f};

    #pragma unroll
    for (int kk = 0; kk < 2; ++kk){
        short8 af[4];
        #pragma unroll
        for (int mt = 0; mt < 4; ++mt){
            int tile = 4*w + mt;
            af[mt] = *((const short8*)&bfA[(tile*2 + kk)*64 + (lane ^ (tile & 7))]);
        }
        #pragma unroll
        for (int nt = 0; nt < 8; ++nt){
            short8 bfr = *((const short8*)&bfB[(nt*2 + kk)*64 + lane]);
            #pragma unroll
            for (int mt = 0; mt < 4; ++mt)
                acc[mt][nt] = __builtin_amdgcn_mfma_f32_16x16x32_bf16(af[mt], bfr, acc[mt][nt], 0, 0, 0);
        }
    }

    // epilogue: group g (32 samples) = m-tiles (2g,2g+1). In-reg 8-value
    // reduce, then 2-stage cross-quad butterfly; quad0 writes coalesced rows.
    float stS[8], stQ[8];
    #pragma unroll
    for (int nt = 0; nt < 8; ++nt){ stS[nt] = 0.0f; stQ[nt] = 0.0f; }

    #pragma unroll
    for (int g = 0; g < 2; ++g){
        const size_t gg = (size_t)(blockIdx.x*8 + w*2 + g);
        #pragma unroll
        for (int nt = 0; nt < 8; ++nt){
            f32x4 a0 = acc[2*g][nt], a1 = acc[2*g+1][nt];
            float mx = fmaxf(fmaxf(fmaxf(a0[0], a0[1]), fmaxf(a0[2], a0[3])),
                             fmaxf(fmaxf(a1[0], a1[1]), fmaxf(a1[2], a1[3])));
            float mn = fminf(fminf(fminf(a0[0], a0[1]), fminf(a0[2], a0[3])),
                             fminf(fminf(a1[0], a1[1]), fminf(a1[2], a1[3])));
            float sm = (a0[0]+a0[1]) + (a0[2]+a0[3]) + (a1[0]+a1[1]) + (a1[2]+a1[3]);
            float sq = a0[0]*a0[0];
            sq = fmaf(a0[1], a0[1], sq); sq = fmaf(a0[2], a0[2], sq); sq = fmaf(a0[3], a0[3], sq);
            sq = fmaf(a1[0], a1[0], sq); sq = fmaf(a1[1], a1[1], sq); sq = fmaf(a1[2], a1[2], sq);
            sq = fmaf(a1[3], a1[3], sq);
            #pragma unroll
            for (int st = 16; st < 64; st <<= 1){
                mx = fmaxf(mx, __shfl_xor(mx, st, 64));
                mn = fminf(mn, __shfl_xor(mn, st, 64));
                sm += __shfl_xor(sm, st, 64);
                sq += __shfl_xor(sq, st, 64);
            }
            if (lane < 16){
                gmax[gg*128 + nt*16 + lane] = mx;
                gmin[gg*128 + nt*16 + lane] = mn;
            }
            stS[nt] += sm; stQ[nt] += sq;
        }
    }
    if (lane < 16){
        #pragma unroll
        for (int nt = 0; nt < 8; ++nt){
            atomicAdd(&sSum[nt*16 + lane], stS[nt]);
            atomicAdd(&sSq[nt*16 + lane],  stQ[nt]);
        }
    }
    __syncthreads();
    if (t < 128){
        atomicAdd(&gsum[rep*128 + t], sSum[t]);
        atomicAdd(&gsq[rep*128 + t],  sSq[t]);
    }
}

// fold BN into affine: reduce REP replicas, then s = g*rsqrt(var+eps),
// t = b - mu*s
__global__ void k_fold(const float* __restrict__ sum, const float* __restrict__ sumsq,
                       const float* __restrict__ gW, const float* __restrict__ bW,
                       float* __restrict__ prm, int C){
    int c = threadIdx.x;
    if (c < C){
        float s = 0.0f, q = 0.0f;
        for (int r = 0; r < REP; ++r){
            s += sum[r*C + c];
            q += sumsq[r*C + c];
        }
        const float inv = 1.0f / (float)NT;
        float mu  = s * inv;
        float var = q * inv - mu*mu;
        float sc  = gW[c] / sqrtf(var + 1e-5f);
        prm[c]     = sc;
        prm[C + c] = bW[c] - mu*sc;
    }
}

// ---------------------------------------------------------------------------
// out[b][o][m] = ReLU(s * (s>=0 ? gmax : gmin) + t); LDS-transpose version —
// reads coalesce over o (512B rows), writes coalesce over m. Tile stride 129
// -> conflict-free both sides.
// ---------------------------------------------------------------------------
__global__ __launch_bounds__(256) void k_final(const float* __restrict__ gmax,
                                               const float* __restrict__ gmin,
                                               const float* __restrict__ prm,
                                               float* __restrict__ out){
    __shared__ float tile[32][129];
    __shared__ float sS[128], sT[128];
    const int t   = threadIdx.x;
    const int blk = blockIdx.x;          // 512 blocks: b = blk>>5, mchunk = blk&31
    const int b   = blk >> 5;
    const int m0  = (blk & 31) * 32;
    if (t < 128){ sS[t] = prm[t]; sT[t] = prm[128 + t]; }
    __syncthreads();
    #pragma unroll
    for (int i = 0; i < 16; ++i){
        int v  = i*256 + t;
        int ml = v >> 7, o = v & 127;
        float sc = sS[o];
        size_t gi = (size_t)(b*M_ + m0 + ml)*128 + o;
        float val = (sc >= 0.0f) ? gmax[gi] : gmin[gi];
        tile[ml][o] = fmaxf(fmaf(val, sc, sT[o]), 0.0f);
    }
    __syncthreads();
    #pragma unroll
    for (int i = 0; i < 16; ++i){
        int v  = i*256 + t;
        int o  = v >> 5, ml = v & 31;
        out[((size_t)(b*128 + o))*M_ + m0 + ml] = tile[ml][o];
    }
}

// ---------------------------------------------------------------------------
extern "C" void kernel_launch(void* const* d_in, const int* in_sizes, int n_in,
                              void* d_out, int out_size, void* d_ws, size_t ws_size,
                              hipStream_t stream){
    const float* loc  = (const float*)d_in[0];
    const float* nloc = (const float*)d_in[1];
    const float* feat = (const float*)d_in[2];
    const float* W1   = (const float*)d_in[3];
    const float* g1   = (const float*)d_in[4];
    const float* b1   = (const float*)d_in[5];
    const float* W2   = (const float*)d_in[6];
    const float* g2   = (const float*)d_in[7];
    const float* b2   = (const float*)d_in[8];
    const float* W3   = (const float*)d_in[9];
    const float* g3   = (const float*)d_in[10];
    const float* b3   = (const float*)d_in[11];
    float* out = (float*)d_out;

    char* ws = (char*)d_ws;
    float* prm1  = (float*)(ws + 2048);              // 128 f
    float* prm2  = (float*)(ws + 2048 + 512);        // 128 f
    float* prm3  = (float*)(ws + 2048 + 1024);       // 256 f -> ends 4096
    int*   idx   = (int*)(ws + 4096);                // 2 MB
    float* gmax  = (float*)(ws + 2101248);           // 8 MB [BM][128]
    float* gmin  = (float*)(ws + 10489856);          // 8 MB
    float* featT = (float*)(ws + 18878464);          // 16 MB [B][N][64]
    u16*   y1    = (u16*)(ws + 35655680);            // 64 MB [64][NT]
    u16*   y2    = (u16*)(ws + 102764544);           // 64 MB  (ws >= 170 MB proven)
    // locP (1 MB) aliases gmax[0..1MB): dead before conv3m writes gmax.
    float4* locP = (float4*)gmax;
    // conv1/conv2 stat replicas (64 KB) alias gmax[1MB..1MB+64KB): read by
    // fold1/fold2, both stream-ordered before conv3m's first gmax write.
    float* rep12 = (float*)(ws + 2101248 + 1048576);
    float* sum1 = rep12;            // [REP][64]
    float* sq1  = rep12 + REP*64;
    float* sum2 = rep12 + 2*REP*64;
    float* sq2  = rep12 + 3*REP*64;
    // conv3 stat replicas (64 KB) alias featT: featT is dead after conv1m.
    float* rep3 = (float*)featT;
    float* sum3 = rep3;             // [REP][128]
    float* sq3  = rep3 + REP*128;

    hipMemsetAsync(rep12, 0, 4*REP*64*sizeof(float), stream);

    k_feat<<<dim3(N_/64, B_), 256, 0, stream>>>(feat, featT);
    k_prep<<<(B_*N_)/256, 256, 0, stream>>>(loc, locP);
    k_knn<<<B_*M_, 256, 0, stream>>>(locP, nloc, idx);

    k_conv1m<<<NT/128, 256, 0, stream>>>(idx, loc, nloc, featT, W1, y1, sum1, sq1);
    k_fold<<<1, 128, 0, stream>>>(sum1, sq1, g1, b1, prm1, 64);
    // featT dead from here: zero conv3's replicas in its region
    hipMemsetAsync(rep3, 0, 2*REP*128*sizeof(float), stream);

    k_conv2m<<<NT/256, 256, 0, stream>>>(y1, W2, prm1, y2, sum2, sq2);
    k_fold<<<1, 128, 0, stream>>>(sum2, sq2, g2, b2, prm2, 64);

    k_conv3m<<<NT/256, 256, 0, stream>>>(y2, W3, prm2, sum3, sq3, gmax, gmin);
    k_fold<<<1, 128, 0, stream>>>(sum3, sq3, g3, b3, prm3, 128);

    k_final<<<dim3(B_*32), 256, 0, stream>>>(gmax, gmin, prm3, out);
}

// Round 10
// 369.130 us; speedup vs baseline: 1.0774x; 1.0774x over previous
//
#include <hip/hip_runtime.h>
#include <stdint.h>

// Problem constants
#define B_   16
#define N_   4096
#define M_   1024
#define NT   (B_*M_*32)      // 524288 samples
#define BM   (B_*M_)         // 16384 (b,m) groups
#define REP  64              // stats-accumulator replicas (atomic decontention)

typedef unsigned short u16;
typedef unsigned long long u64;
typedef __attribute__((ext_vector_type(8))) short short8;   // 8 bf16 (4 VGPRs)
typedef __attribute__((ext_vector_type(4))) float f32x4;    // MFMA C/D

union FragU { uint4 u; short8 s; };

__device__ __forceinline__ float bf2f(u16 u){
    return __uint_as_float(((unsigned int)u) << 16);
}
__device__ __forceinline__ u16 f2bf(float f){
    unsigned int u = __float_as_uint(f);
    return (u16)((u + 0x7FFFu + ((u >> 16) & 1u)) >> 16);
}

// ---------------------------------------------------------------------------
// features [B][64][N] f32 -> featT [B][N][64] f32
// ---------------------------------------------------------------------------
__global__ __launch_bounds__(256) void k_feat(const float* __restrict__ feat,
                                              float* __restrict__ featT){
    __shared__ float tile[64][65];
    int b  = blockIdx.y;
    int n0 = blockIdx.x * 64;
    for (int t = threadIdx.x; t < 4096; t += 256){
        int c = t >> 6, n = t & 63;
        tile[c][n] = feat[((size_t)(b*64 + c))*N_ + n0 + n];
    }
    __syncthreads();
    for (int t = threadIdx.x; t < 4096; t += 256){
        int n = t >> 6, c = t & 63;
        featT[((size_t)(b*N_) + n0 + n)*64 + c] = tile[c][n];
    }
}

// ---------------------------------------------------------------------------
// pack loc -> (x,y,z,x2): removes per-query recompute of x2 in k_knn and
// turns the point load into one aligned dwordx4.
// ---------------------------------------------------------------------------
__global__ __launch_bounds__(256) void k_prep(const float* __restrict__ locF,
                                              float4* __restrict__ locP){
    int i = blockIdx.x*256 + threadIdx.x;   // B_*N_ = 65536 points
    float lx = locF[(size_t)i*3+0], ly = locF[(size_t)i*3+1], lz = locF[(size_t)i*3+2];
    float x2 = __fadd_rn(__fadd_rn(__fmul_rn(lx,lx), __fmul_rn(ly,ly)), __fmul_rn(lz,lz));
    locP[i] = make_float4(lx, ly, lz, x2);
}

// ---------------------------------------------------------------------------
// exact KNN (32 smallest of 4096): value-domain linear bucket select.
// This is the r5/r8 lockstep version — empirically a strong local optimum.
// LEDGER of failed restructures (do not re-attempt without new evidence):
//  - r7 raw-bit radix-256: top byte = sign+exponent -> all keys in 3-5
//    buckets -> LDS same-address atomic serialization (conflicts 5.35M->37M),
//    103->194 us. Bucket DISTRIBUTION, not ops/elem, governs cost.
//  - r9 wave-autonomous (per-wave top-32 + 128->32 merge): deleted barriers
//    but added 4x rank work + serial 128-iter merge loops; occupancy already
//    hides barrier idle (m114 wave-overlap). 114->129 us.
// ---------------------------------------------------------------------------
__global__ __launch_bounds__(256) void k_knn(const float4* __restrict__ locP,
                                             const float* __restrict__ nlocF,
                                             int* __restrict__ idxOut){
    const int tid  = threadIdx.x;
    const int lane = tid & 63, wv = tid >> 6;
    const int q    = blockIdx.x;
    const int b    = q >> 10, m = q & 1023;

    float qx = nlocF[(size_t)(b*M_ + m)*3 + 0];
    float qy = nlocF[(size_t)(b*M_ + m)*3 + 1];
    float qz = nlocF[(size_t)(b*M_ + m)*3 + 2];
    float y2 = __fadd_rn(__fadd_rn(__fmul_rn(qx,qx), __fmul_rn(qy,qy)), __fmul_rn(qz,qz));

    unsigned int key[16];
    const float4* lb = locP + (size_t)b*N_;
    #pragma unroll
    for (int i = 0; i < 16; ++i){
        int n = i*256 + tid;
        float4 p = lb[n];
        float dt = __fadd_rn(__fadd_rn(__fmul_rn(qx,p.x), __fmul_rn(qy,p.y)), __fmul_rn(qz,p.z));
        float d2 = __fsub_rn(__fadd_rn(y2, p.w), __fmul_rn(2.0f, dt));
        d2 = fmaxf(d2, 0.0f);
        key[i] = __float_as_uint(d2);
    }

    __shared__ unsigned int hist[4][256];
    __shared__ float wmm[4][2];
    __shared__ u64 cand[128];
    __shared__ int sOut[32];
    __shared__ int outCnt, candCnt;

    float lmin = 3.4e38f, lmax = 0.0f;
    #pragma unroll
    for (int i = 0; i < 16; ++i){
        float kf = __uint_as_float(key[i]);
        lmin = fminf(lmin, kf); lmax = fmaxf(lmax, kf);
    }
    #pragma unroll
    for (int st = 1; st < 64; st <<= 1){
        lmin = fminf(lmin, __shfl_xor(lmin, st, 64));
        lmax = fmaxf(lmax, __shfl_xor(lmax, st, 64));
    }
    if (tid == 0){ outCnt = 0; candCnt = 0; }
    if (lane == 0){ wmm[wv][0] = lmin; wmm[wv][1] = lmax; }
    __syncthreads();
    float lo = fminf(fminf(wmm[0][0], wmm[1][0]), fminf(wmm[2][0], wmm[3][0]));
    float hi = fmaxf(fmaxf(wmm[0][1], wmm[1][1]), fmaxf(wmm[2][1], wmm[3][1]));

    unsigned int act = 0xFFFFu;
    int bkt[16];
    int R = 32;

    for (int lvl = 0; lvl < 8; ++lvl){
        float scale = 255.0f / fmaxf(hi - lo, 1e-35f);
        ((uint4*)hist)[tid] = make_uint4(0,0,0,0);
        __syncthreads();
        #pragma unroll
        for (int i = 0; i < 16; ++i){
            if (act & (1u << i)){
                float kf = __uint_as_float(key[i]);
                int bb = (int)((kf - lo) * scale);
                bb = bb < 0 ? 0 : (bb > 255 ? 255 : bb);
                bkt[i] = bb;
                atomicAdd(&hist[wv][bb], 1u);
            }
        }
        __syncthreads();
        uint4 ha = *(const uint4*)&hist[0][lane << 2];
        uint4 hb = *(const uint4*)&hist[1][lane << 2];
        uint4 hc = *(const uint4*)&hist[2][lane << 2];
        uint4 hd = *(const uint4*)&hist[3][lane << 2];
        uint4 h = make_uint4(ha.x+hb.x+hc.x+hd.x, ha.y+hb.y+hc.y+hd.y,
                             ha.z+hb.z+hc.z+hd.z, ha.w+hb.w+hc.w+hd.w);
        int tot = (int)(h.x + h.y + h.z + h.w);
        int v = tot;
        #pragma unroll
        for (int st = 1; st < 64; st <<= 1){
            int u = __shfl_up(v, st, 64);
            if (lane >= st) v += u;
        }
        u64 bal = __ballot(v >= R);
        int Ls = __ffsll((unsigned long long)bal) - 1;
        int exclS = __shfl(v - tot, Ls, 64);
        int hx = __shfl((int)h.x, Ls, 64), hy = __shfl((int)h.y, Ls, 64);
        int hz = __shfl((int)h.z, Ls, 64), hw = __shfl((int)h.w, Ls, 64);
        int c0 = exclS + hx, c1 = c0 + hy, c2 = c1 + hz;
        int jj    = (c0 >= R) ? 0 : (c1 >= R) ? 1 : (c2 >= R) ? 2 : 3;
        int below = (jj == 0) ? exclS : (jj == 1) ? c0 : (jj == 2) ? c1 : c2;
        int cnt   = (jj == 0) ? hx : (jj == 1) ? hy : (jj == 2) ? hz : hw;
        int qb = Ls*4 + jj;
        R -= below;
        bool brk = (cnt <= 128) || (lvl == 7);

        float nlo = 3.4e38f, nhi = 0.0f;
        #pragma unroll
        for (int i = 0; i < 16; ++i){
            if (act & (1u << i)){
                int bb = bkt[i];
                if (bb < qb){
                    int pos = atomicAdd(&outCnt, 1);
                    if (pos < 32) sOut[pos] = i*256 + tid;
                    act &= ~(1u << i);
                } else if (bb > qb){
                    act &= ~(1u << i);
                } else if (!brk){
                    float kf = __uint_as_float(key[i]);
                    nlo = fminf(nlo, kf); nhi = fmaxf(nhi, kf);
                }
            }
        }
        if (brk) break;
        #pragma unroll
        for (int st = 1; st < 64; st <<= 1){
            nlo = fminf(nlo, __shfl_xor(nlo, st, 64));
            nhi = fmaxf(nhi, __shfl_xor(nhi, st, 64));
        }
        __syncthreads();
        if (lane == 0){ wmm[wv][0] = nlo; wmm[wv][1] = nhi; }
        __syncthreads();
        lo = fminf(fminf(wmm[0][0], wmm[1][0]), fminf(wmm[2][0], wmm[3][0]));
        hi = fmaxf(fmaxf(wmm[0][1], wmm[1][1]), fmaxf(wmm[2][1], wmm[3][1]));
    }

    #pragma unroll
    for (int i = 0; i < 16; ++i){
        if (act & (1u << i)){
            int pos = atomicAdd(&candCnt, 1);
            if (pos < 128) cand[pos] = (((u64)key[i]) << 32) | (unsigned int)(i*256 + tid);
        }
    }
    __syncthreads();
    int c = candCnt < 128 ? candCnt : 128;
    int base = outCnt;
    if (tid < c){
        u64 me = cand[tid];
        int rank = 0;
        for (int j = 0; j < c; ++j) rank += (cand[j] < me) ? 1 : 0;
        if (rank < R) sOut[base + rank] = (int)(me & 0xFFFFFFFFull);
    }
    __syncthreads();
    if (tid < 32) idxOut[(size_t)q*32 + tid] = sOut[tid];
}

// ---------------------------------------------------------------------------
// conv1 via MFMA, direct-to-register A gather; stats via replicated atomics.
// ---------------------------------------------------------------------------
__global__ __launch_bounds__(256) void k_conv1m(const int* __restrict__ idx,
                                                const float* __restrict__ locF,
                                                const float* __restrict__ nlocF,
                                                const float* __restrict__ featT,
                                                const float* __restrict__ W1,
                                                u16* __restrict__ y1,
                                                float* __restrict__ gsum,
                                                float* __restrict__ gsq){
    __shared__ uint4 bfB[4*5*64];   // 20 KB: frag (nt,kk) at (nt*5+kk)*64 + lane
    __shared__ u16  tileT[64*136];  // 17 KB transpose-out, stride 136 u16 = 272 B
    __shared__ float sSum[64], sSq[64];
    const int t   = threadIdx.x;
    const int bid = blockIdx.x;
    const int rep = bid & (REP-1);
    const int swz = (bid & 7)*512 + (bid >> 3);   // XCD-contiguous chunks
    const int s0  = swz * 128;
    const int b   = s0 >> 15;

    if (t < 64){ sSum[t] = 0.0f; sSq[t] = 0.0f; }

    // stage B': W1 hi duplicated in both halves of each k'-pair word
    #pragma unroll
    for (int rp = 0; rp < 5; ++rp){
        int cid = rp*256 + t;             // = (nt*5+kk)*64 + ln, cid < 1280
        int ln  = cid & 63;
        int kk  = (cid >> 6) % 5;
        int nt  = cid / 320;
        int o   = nt*16 + (ln & 15);
        int qq  = ln >> 4;
        int cb  = kk*16 + qq*4;           // phys channel base of this uint4
        unsigned int d[4];
        #pragma unroll
        for (int h = 0; h < 4; ++h){
            int c = cb + h;
            float wv = (c < 64) ? W1[o*67 + 3 + c] : ((c < 67) ? W1[o*67 + (c - 64)] : 0.0f);
            unsigned int wh = (unsigned int)f2bf(wv);
            d[h] = wh | (wh << 16);
        }
        bfB[cid] = make_uint4(d[0], d[1], d[2], d[3]);
    }

    // direct A gather: wave w -> m-tiles 2w,2w+1; lane q=l>>4 selects k-quad
    const int w = t >> 6, lane = t & 63;
    const int m15 = lane & 15, q = lane >> 4;

    int nrow[2], sg[2];
    float4 fa[2][4];
    #pragma unroll
    for (int mt = 0; mt < 2; ++mt){
        int sl = (2*w + mt)*16 + m15;
        sg[mt] = s0 + sl;
        int n = idx[sg[mt]]; if ((unsigned)n >= N_) n = 0;
        nrow[mt] = n;
        const float4* fp = (const float4*)&featT[((size_t)(b*N_) + n)*64];
        #pragma unroll
        for (int kq = 0; kq < 4; ++kq)
            fa[mt][kq] = fp[kq*4 + q];     // phys cols kq*16+q*4 .. +3
    }
    // xyz fragment (kk=4): only q==0 lanes carry data (phys c 64..67)
    uint4 axyz[2];
    axyz[0] = make_uint4(0,0,0,0); axyz[1] = make_uint4(0,0,0,0);
    if (q == 0){
        #pragma unroll
        for (int mt = 0; mt < 2; ++mt){
            int n = nrow[mt];
            int m = (sg[mt] >> 5) & 1023;
            const float* lp = &locF[(size_t)(b*N_ + n)*3];
            const float* qp = &nlocF[(size_t)(b*M_ + m)*3];
            unsigned int dd[3];
            #pragma unroll
            for (int e = 0; e < 3; ++e){
                float r  = lp[e] - qp[e];
                u16 hi   = f2bf(r);
                float lo = r - bf2f(hi);
                dd[e] = (unsigned int)hi | (((unsigned int)f2bf(lo)) << 16);
            }
            axyz[mt] = make_uint4(dd[0], dd[1], dd[2], 0u);
        }
    }
    __syncthreads();   // bfB ready (also covers sSum init)

    f32x4 acc[2][4];
    #pragma unroll
    for (int mt = 0; mt < 2; ++mt)
        #pragma unroll
        for (int nt = 0; nt < 4; ++nt)
            acc[mt][nt] = (f32x4){0.0f, 0.0f, 0.0f, 0.0f};

    #pragma unroll
    for (int kk = 0; kk < 5; ++kk){
        FragU af[2];
        #pragma unroll
        for (int mt = 0; mt < 2; ++mt){
            if (kk < 4){
                float4 f = fa[mt][kk];
                float fv[4] = {f.x, f.y, f.z, f.w};
                unsigned int d[4];
                #pragma unroll
                for (int e = 0; e < 4; ++e){
                    u16 hi   = f2bf(fv[e]);
                    float lo = fv[e] - bf2f(hi);
                    d[e] = (unsigned int)hi | (((unsigned int)f2bf(lo)) << 16);
                }
                af[mt].u = make_uint4(d[0], d[1], d[2], d[3]);
            } else {
                af[mt].u = axyz[mt];
            }
        }
        #pragma unroll
        for (int nt = 0; nt < 4; ++nt){
            FragU bu; bu.u = bfB[(nt*5 + kk)*64 + lane];
            #pragma unroll
            for (int mt = 0; mt < 2; ++mt)
                acc[mt][nt] = __builtin_amdgcn_mfma_f32_16x16x32_bf16(af[mt].s, bu.s, acc[mt][nt], 0, 0, 0);
        }
    }

    // fused stats: channel o = nt*16 + (lane&15); butterfly strides 16,32
    {
        float st4[4], sq4[4];
        #pragma unroll
        for (int nt = 0; nt < 4; ++nt){ st4[nt] = 0.0f; sq4[nt] = 0.0f; }
        #pragma unroll
        for (int mt = 0; mt < 2; ++mt)
            #pragma unroll
            for (int nt = 0; nt < 4; ++nt){
                f32x4 a = acc[mt][nt];
                st4[nt] += (a[0] + a[1]) + (a[2] + a[3]);
                float qv = a[0]*a[0];
                qv = fmaf(a[1], a[1], qv); qv = fmaf(a[2], a[2], qv); qv = fmaf(a[3], a[3], qv);
                sq4[nt] += qv;
            }
        #pragma unroll
        for (int st = 16; st < 64; st <<= 1){
            #pragma unroll
            for (int nt = 0; nt < 4; ++nt){
                st4[nt] += __shfl_xor(st4[nt], st, 64);
                sq4[nt] += __shfl_xor(sq4[nt], st, 64);
            }
        }
        if (lane < 16){
            #pragma unroll
            for (int nt = 0; nt < 4; ++nt){
                atomicAdd(&sSum[nt*16 + lane], st4[nt]);
                atomicAdd(&sSq[nt*16 + lane],  sq4[nt]);
            }
        }
    }

    // transpose D -> channel-major bf16 via padded LDS tile
    #pragma unroll
    for (int mt = 0; mt < 2; ++mt){
        int s_base = w*32 + mt*16 + (lane >> 4)*4;
        #pragma unroll
        for (int nt = 0; nt < 4; ++nt){
            int o = nt*16 + (lane & 15);
            f32x4 a = acc[mt][nt];
            unsigned int p01 = (unsigned int)f2bf(a[0]) | (((unsigned int)f2bf(a[1])) << 16);
            unsigned int p23 = (unsigned int)f2bf(a[2]) | (((unsigned int)f2bf(a[3])) << 16);
            *(unsigned int*)&tileT[o*136 + s_base]     = p01;
            *(unsigned int*)&tileT[o*136 + s_base + 2] = p23;
        }
    }
    __syncthreads();

    // coalesced channel-major store: thread t -> channel c=t>>2, 32-sample chunk
    {
        int c  = t >> 2;
        int g0 = (t & 3)*32;
        #pragma unroll
        for (int j = 0; j < 4; ++j){
            uint4 v = *(const uint4*)&tileT[c*136 + g0 + j*8];
            *(uint4*)&y1[(size_t)c*NT + s0 + g0 + j*8] = v;
        }
    }
    if (t < 64){
        atomicAdd(&gsum[rep*64 + t], sSum[t]);
        atomicAdd(&gsq[rep*64 + t],  sSq[t]);
    }
}

// ---------------------------------------------------------------------------
// conv2 via MFMA (verified): A = affine+relu(y1) frags (XOR-swizzled LDS),
// B = W2 frags; transpose-out via padded LDS; fused per-channel stats
// (replicated atomics, r5).
// ---------------------------------------------------------------------------
__global__ __launch_bounds__(256) void k_conv2m(const u16* __restrict__ yin,
                                                const float* __restrict__ W2,
                                                const float* __restrict__ prm,
                                                u16* __restrict__ yout,
                                                float* __restrict__ gsum,
                                                float* __restrict__ gsq){
    __shared__ uint4 bfA[2048];     // act frags: (mtg*2+kk)*64 + (l64 ^ (mtg&7)) (32 KB)
    __shared__ uint4 bfB[512];      // W2 frags:  (nt*2+kk)*64 + lane             (8 KB)
    __shared__ u16  tileT[64*264];  // transpose-out, stride 264 u16 = 528 B     (33 KB)
    __shared__ float sS[64], sT[64];
    __shared__ float sSum[64], sSq[64];
    const int t   = threadIdx.x;
    const int rep = blockIdx.x & (REP-1);
    const int s0  = blockIdx.x * 256;

    if (t < 64){ sS[t] = prm[t]; sT[t] = prm[64 + t]; sSum[t] = 0.0f; sSq[t] = 0.0f; }
    __syncthreads();

    // stage B: W2 [64][64] f32 -> bf16 frags (n=o within tile), nt in [0,4)
    #pragma unroll
    for (int rp = 0; rp < 2; ++rp){
        int cid = rp*256 + t;
        int ln  = cid & 63;
        int kk  = (cid >> 6) & 1;
        int nt  = cid >> 7;
        int o   = nt*16 + (ln & 15);
        int k0  = kk*32 + (ln >> 4)*8;
        const float* wp = &W2[o*64 + k0];
        unsigned int d[4];
        #pragma unroll
        for (int h = 0; h < 4; ++h)
            d[h] = (unsigned int)f2bf(wp[2*h]) | (((unsigned int)f2bf(wp[2*h+1])) << 16);
        bfB[cid] = make_uint4(d[0], d[1], d[2], d[3]);
    }

    // stage A: y1 channel-major; affine+relu; m=sample frags, XOR-swizzled
    {
        int oct = t >> 5;            // channels oct*8..+7: kk=oct>>2, qd=oct&3
        int sg  = t & 31;            // samples sg*8..+7 (local)
        int c0  = oct*8;
        int kk  = oct >> 2;
        int qd  = oct & 3;
        u16 rb[8][8];                // [j (=c-c0)][i (=sample)] — constant-indexed only
        #pragma unroll
        for (int j = 0; j < 8; ++j){
            int c = c0 + j;
            uint4 pk = *(const uint4*)&yin[(size_t)c*NT + s0 + sg*8];
            float sc = sS[c], tb = sT[c];
            unsigned int w4[4] = {pk.x, pk.y, pk.z, pk.w};
            #pragma unroll
            for (int h = 0; h < 4; ++h){
                rb[j][2*h]   = f2bf(fmaxf(fmaf(bf2f((u16)(w4[h] & 0xFFFF)), sc, tb), 0.0f));
                rb[j][2*h+1] = f2bf(fmaxf(fmaf(bf2f((u16)(w4[h] >> 16)),   sc, tb), 0.0f));
            }
        }
        #pragma unroll
        for (int i = 0; i < 8; ++i){            // i is a literal after unroll
            int s   = sg*8 + i;
            int mtg = s >> 4, m15 = s & 15;
            int l64 = qd*16 + m15;
            int cb  = (mtg*2 + kk)*64 + (l64 ^ (mtg & 7));   // XOR swizzle
            unsigned int d[4];
            #pragma unroll
            for (int h = 0; h < 4; ++h)
                d[h] = (unsigned int)rb[2*h][i] | (((unsigned int)rb[2*h+1][i]) << 16);
            bfA[cb] = make_uint4(d[0], d[1], d[2], d[3]);
        }
    }
    __syncthreads();

    // MFMA: wave w -> m-tiles 4w..4w+3 (samples w*64..+63), 4 n-tiles (64 ch)
    const int w = t >> 6, lane = t & 63;
    f32x4 acc[4][4];
    #pragma unroll
    for (int mt = 0; mt < 4; ++mt)
        #pragma unroll
        for (int nt = 0; nt < 4; ++nt)
            acc[mt][nt] = (f32x4){0.0f, 0.0f, 0.0f, 0.0f};

    #pragma unroll
    for (int kk = 0; kk < 2; ++kk){
        short8 af[4];
        #pragma unroll
        for (int mt = 0; mt < 4; ++mt){
            int tile = 4*w + mt;
            af[mt] = *((const short8*)&bfA[(tile*2 + kk)*64 + (lane ^ (tile & 7))]);
        }
        #pragma unroll
        for (int nt = 0; nt < 4; ++nt){
            short8 bfr = *((const short8*)&bfB[(nt*2 + kk)*64 + lane]);
            #pragma unroll
            for (int mt = 0; mt < 4; ++mt)
                acc[mt][nt] = __builtin_amdgcn_mfma_f32_16x16x32_bf16(af[mt], bfr, acc[mt][nt], 0, 0, 0);
        }
    }

    // fused stats: channel o = nt*16 + (lane&15); butterfly strides 16,32
    {
        float st4[4], sq4[4];
        #pragma unroll
        for (int nt = 0; nt < 4; ++nt){ st4[nt] = 0.0f; sq4[nt] = 0.0f; }
        #pragma unroll
        for (int mt = 0; mt < 4; ++mt)
            #pragma unroll
            for (int nt = 0; nt < 4; ++nt){
                f32x4 a = acc[mt][nt];
                st4[nt] += (a[0] + a[1]) + (a[2] + a[3]);
                float qq = a[0]*a[0];
                qq = fmaf(a[1], a[1], qq); qq = fmaf(a[2], a[2], qq); qq = fmaf(a[3], a[3], qq);
                sq4[nt] += qq;
            }
        #pragma unroll
        for (int st = 16; st < 64; st <<= 1){
            #pragma unroll
            for (int nt = 0; nt < 4; ++nt){
                st4[nt] += __shfl_xor(st4[nt], st, 64);
                sq4[nt] += __shfl_xor(sq4[nt], st, 64);
            }
        }
        if (lane < 16){
            #pragma unroll
            for (int nt = 0; nt < 4; ++nt){
                atomicAdd(&sSum[nt*16 + lane], st4[nt]);
                atomicAdd(&sSq[nt*16 + lane],  sq4[nt]);
            }
        }
    }

    // transpose D -> channel-major bf16 via padded LDS tile
    #pragma unroll
    for (int mt = 0; mt < 4; ++mt){
        int s_base = w*64 + mt*16 + (lane >> 4)*4;
        #pragma unroll
        for (int nt = 0; nt < 4; ++nt){
            int o = nt*16 + (lane & 15);
            f32x4 a = acc[mt][nt];
            unsigned int p01 = (unsigned int)f2bf(a[0]) | (((unsigned int)f2bf(a[1])) << 16);
            unsigned int p23 = (unsigned int)f2bf(a[2]) | (((unsigned int)f2bf(a[3])) << 16);
            *(unsigned int*)&tileT[o*264 + s_base]     = p01;
            *(unsigned int*)&tileT[o*264 + s_base + 2] = p23;
        }
    }
    __syncthreads();

    // coalesced channel-major store: thread t -> row c=t>>2, 8x16B chunks
    {
        int c  = t >> 2;
        int g0 = (t & 3)*8;
        #pragma unroll
        for (int j = 0; j < 8; ++j){
            uint4 v = *(const uint4*)&tileT[c*264 + (g0 + j)*8];
            *(uint4*)&yout[(size_t)c*NT + s0 + (g0 + j)*8] = v;
        }
    }
    if (t < 64){
        atomicAdd(&gsum[rep*64 + t], sSum[t]);
        atomicAdd(&gsq[rep*64 + t],  sSq[t]);
    }
}

// ---------------------------------------------------------------------------
// conv3 via MFMA: A = activations (m=sample), B = W3 (n=channel) -> D row =
// sample. Epilogue: in-reg reduce + cross-quad butterfly; gmax/gmin
// [group][o] coalesced; stats via replicated atomics (r5).
// ---------------------------------------------------------------------------
__global__ __launch_bounds__(256) void k_conv3m(const u16* __restrict__ yin,
                                                const float* __restrict__ W3,
                                                const float* __restrict__ prm,
                                                float* __restrict__ gsum, float* __restrict__ gsq,
                                                float* __restrict__ gmax, float* __restrict__ gmin){
    __shared__ uint4 bfA[2048];     // act frags: (mtg*2+kk)*64 + (lane64 ^ (mtg&7))  (32 KB)
    __shared__ uint4 bfB[1024];     // W3 frags:  (nt*2+kk)*64 + lane                 (16 KB)
    __shared__ float sS[64], sT[64];
    __shared__ float sSum[128], sSq[128];
    const int t   = threadIdx.x;
    const int rep = blockIdx.x & (REP-1);
    const int s0  = blockIdx.x * 256;

    if (t < 64){ sS[t] = prm[t]; sT[t] = prm[64 + t]; }
    if (t < 128){ sSum[t] = 0.0f; sSq[t] = 0.0f; }
    __syncthreads();

    // stage B: W3 [128][64] f32 -> bf16 frags (n=channel within tile)
    #pragma unroll
    for (int rp = 0; rp < 4; ++rp){
        int cid = rp*256 + t;
        int ln  = cid & 63;
        int kk  = (cid >> 6) & 1;
        int nt  = cid >> 7;
        int o   = nt*16 + (ln & 15);
        int k0  = kk*32 + (ln >> 4)*8;
        const float* wp = &W3[o*64 + k0];
        unsigned int d[4];
        #pragma unroll
        for (int h = 0; h < 4; ++h)
            d[h] = (unsigned int)f2bf(wp[2*h]) | (((unsigned int)f2bf(wp[2*h+1])) << 16);
        bfB[cid] = make_uint4(d[0], d[1], d[2], d[3]);
    }

    // stage A: y2 channel-major; affine+relu; m=sample frags, XOR-swizzled
    {
        int oct = t >> 5;            // channels oct*8..+7: kk=oct>>2, qd=oct&3
        int sg  = t & 31;            // samples sg*8..+7 (local)
        int c0  = oct*8;
        int kk  = oct >> 2;
        int qd  = oct & 3;
        u16 rb[8][8];                // [j (=c-c0)][i (=sample)] — constant-indexed only
        #pragma unroll
        for (int j = 0; j < 8; ++j){
            int c = c0 + j;
            uint4 pk = *(const uint4*)&yin[(size_t)c*NT + s0 + sg*8];
            float sc = sS[c], tb = sT[c];
            unsigned int w4[4] = {pk.x, pk.y, pk.z, pk.w};
            #pragma unroll
            for (int h = 0; h < 4; ++h){
                rb[j][2*h]   = f2bf(fmaxf(fmaf(bf2f((u16)(w4[h] & 0xFFFF)), sc, tb), 0.0f));
                rb[j][2*h+1] = f2bf(fmaxf(fmaf(bf2f((u16)(w4[h] >> 16)),   sc, tb), 0.0f));
            }
        }
        #pragma unroll
        for (int i = 0; i < 8; ++i){            // i is a literal after unroll
            int s   = sg*8 + i;
            int mtg = s >> 4, m15 = s & 15;
            int l64 = qd*16 + m15;
            int cb  = (mtg*2 + kk)*64 + (l64 ^ (mtg & 7));   // XOR swizzle
            unsigned int d[4];
            #pragma unroll
            for (int h = 0; h < 4; ++h)
                d[h] = (unsigned int)rb[2*h][i] | (((unsigned int)rb[2*h+1][i]) << 16);
            bfA[cb] = make_uint4(d[0], d[1], d[2], d[3]);
        }
    }
    __syncthreads();

    // MFMA: wave w -> m-tiles 4w..4w+3 (samples w*64..+63), all 8 n-tiles
    const int w = t >> 6, lane = t & 63;
    f32x4 acc[4][8];
    #pragma unroll
    for (int mt = 0; mt < 4; ++mt)
        #pragma unroll
        for (int nt = 0; nt < 8; ++nt)
            acc[mt][nt] = (f32x4){0.0f, 0.0f, 0.0f, 0.0f};

    #pragma unroll
    for (int kk = 0; kk < 2; ++kk){
        short8 af[4];
        #pragma unroll
        for (int mt = 0; mt < 4; ++mt){
            int tile = 4*w + mt;
            af[mt] = *((const short8*)&bfA[(tile*2 + kk)*64 + (lane ^ (tile & 7))]);
        }
        #pragma unroll
        for (int nt = 0; nt < 8; ++nt){
            short8 bfr = *((const short8*)&bfB[(nt*2 + kk)*64 + lane]);
            #pragma unroll
            for (int mt = 0; mt < 4; ++mt)
                acc[mt][nt] = __builtin_amdgcn_mfma_f32_16x16x32_bf16(af[mt], bfr, acc[mt][nt], 0, 0, 0);
        }
    }

    // epilogue: group g (32 samples) = m-tiles (2g,2g+1). In-reg 8-value
    // reduce, then 2-stage cross-quad butterfly; quad0 writes coalesced rows.
    float stS[8], stQ[8];
    #pragma unroll
    for (int nt = 0; nt < 8; ++nt){ stS[nt] = 0.0f; stQ[nt] = 0.0f; }

    #pragma unroll
    for (int g = 0; g < 2; ++g){
        const size_t gg = (size_t)(blockIdx.x*8 + w*2 + g);
        #pragma unroll
        for (int nt = 0; nt < 8; ++nt){
            f32x4 a0 = acc[2*g][nt], a1 = acc[2*g+1][nt];
            float mx = fmaxf(fmaxf(fmaxf(a0[0], a0[1]), fmaxf(a0[2], a0[3])),
                             fmaxf(fmaxf(a1[0], a1[1]), fmaxf(a1[2], a1[3])));
            float mn = fminf(fminf(fminf(a0[0], a0[1]), fminf(a0[2], a0[3])),
                             fminf(fminf(a1[0], a1[1]), fminf(a1[2], a1[3])));
            float sm = (a0[0]+a0[1]) + (a0[2]+a0[3]) + (a1[0]+a1[1]) + (a1[2]+a1[3]);
            float sq = a0[0]*a0[0];
            sq = fmaf(a0[1], a0[1], sq); sq = fmaf(a0[2], a0[2], sq); sq = fmaf(a0[3], a0[3], sq);
            sq = fmaf(a1[0], a1[0], sq); sq = fmaf(a1[1], a1[1], sq); sq = fmaf(a1[2], a1[2], sq);
            sq = fmaf(a1[3], a1[3], sq);
            #pragma unroll
            for (int st = 16; st < 64; st <<= 1){
                mx = fmaxf(mx, __shfl_xor(mx, st, 64));
                mn = fminf(mn, __shfl_xor(mn, st, 64));
                sm += __shfl_xor(sm, st, 64);
                sq += __shfl_xor(sq, st, 64);
            }
            if (lane < 16){
                gmax[gg*128 + nt*16 + lane] = mx;
                gmin[gg*128 + nt*16 + lane] = mn;
            }
            stS[nt] += sm; stQ[nt] += sq;
        }
    }
    if (lane < 16){
        #pragma unroll
        for (int nt = 0; nt < 8; ++nt){
            atomicAdd(&sSum[nt*16 + lane], stS[nt]);
            atomicAdd(&sSq[nt*16 + lane],  stQ[nt]);
        }
    }
    __syncthreads();
    if (t < 128){
        atomicAdd(&gsum[rep*128 + t], sSum[t]);
        atomicAdd(&gsq[rep*128 + t],  sSq[t]);
    }
}

// fold BN into affine: reduce REP replicas, then s = g*rsqrt(var+eps),
// t = b - mu*s
__global__ void k_fold(const float* __restrict__ sum, const float* __restrict__ sumsq,
                       const float* __restrict__ gW, const float* __restrict__ bW,
                       float* __restrict__ prm, int C){
    int c = threadIdx.x;
    if (c < C){
        float s = 0.0f, q = 0.0f;
        for (int r = 0; r < REP; ++r){
            s += sum[r*C + c];
            q += sumsq[r*C + c];
        }
        const float inv = 1.0f / (float)NT;
        float mu  = s * inv;
        float var = q * inv - mu*mu;
        float sc  = gW[c] / sqrtf(var + 1e-5f);
        prm[c]     = sc;
        prm[C + c] = bW[c] - mu*sc;
    }
}

// ---------------------------------------------------------------------------
// out[b][o][m] = ReLU(s * (s>=0 ? gmax : gmin) + t); LDS-transpose version —
// reads coalesce over o (512B rows), writes coalesce over m. Tile stride 129
// -> conflict-free both sides.
// ---------------------------------------------------------------------------
__global__ __launch_bounds__(256) void k_final(const float* __restrict__ gmax,
                                               const float* __restrict__ gmin,
                                               const float* __restrict__ prm,
                                               float* __restrict__ out){
    __shared__ float tile[32][129];
    __shared__ float sS[128], sT[128];
    const int t   = threadIdx.x;
    const int blk = blockIdx.x;          // 512 blocks: b = blk>>5, mchunk = blk&31
    const int b   = blk >> 5;
    const int m0  = (blk & 31) * 32;
    if (t < 128){ sS[t] = prm[t]; sT[t] = prm[128 + t]; }
    __syncthreads();
    #pragma unroll
    for (int i = 0; i < 16; ++i){
        int v  = i*256 + t;
        int ml = v >> 7, o = v & 127;
        float sc = sS[o];
        size_t gi = (size_t)(b*M_ + m0 + ml)*128 + o;
        float val = (sc >= 0.0f) ? gmax[gi] : gmin[gi];
        tile[ml][o] = fmaxf(fmaf(val, sc, sT[o]), 0.0f);
    }
    __syncthreads();
    #pragma unroll
    for (int i = 0; i < 16; ++i){
        int v  = i*256 + t;
        int o  = v >> 5, ml = v & 31;
        out[((size_t)(b*128 + o))*M_ + m0 + ml] = tile[ml][o];
    }
}

// ---------------------------------------------------------------------------
extern "C" void kernel_launch(void* const* d_in, const int* in_sizes, int n_in,
                              void* d_out, int out_size, void* d_ws, size_t ws_size,
                              hipStream_t stream){
    const float* loc  = (const float*)d_in[0];
    const float* nloc = (const float*)d_in[1];
    const float* feat = (const float*)d_in[2];
    const float* W1   = (const float*)d_in[3];
    const float* g1   = (const float*)d_in[4];
    const float* b1   = (const float*)d_in[5];
    const float* W2   = (const float*)d_in[6];
    const float* g2   = (const float*)d_in[7];
    const float* b2   = (const float*)d_in[8];
    const float* W3   = (const float*)d_in[9];
    const float* g3   = (const float*)d_in[10];
    const float* b3   = (const float*)d_in[11];
    float* out = (float*)d_out;

    char* ws = (char*)d_ws;
    float* prm1  = (float*)(ws + 2048);              // 128 f
    float* prm2  = (float*)(ws + 2048 + 512);        // 128 f
    float* prm3  = (float*)(ws + 2048 + 1024);       // 256 f -> ends 4096
    int*   idx   = (int*)(ws + 4096);                // 2 MB
    float* gmax  = (float*)(ws + 2101248);           // 8 MB [BM][128]
    float* gmin  = (float*)(ws + 10489856);          // 8 MB
    float* featT = (float*)(ws + 18878464);          // 16 MB [B][N][64]
    u16*   y1    = (u16*)(ws + 35655680);            // 64 MB [64][NT]
    u16*   y2    = (u16*)(ws + 102764544);           // 64 MB  (ws >= 170 MB proven)
    // locP (1 MB) aliases gmax[0..1MB): dead before conv3m writes gmax.
    float4* locP = (float4*)gmax;
    // conv1/conv2 stat replicas (64 KB) alias gmax[1MB..1MB+64KB): read by
    // fold1/fold2, both stream-ordered before conv3m's first gmax write.
    float* rep12 = (float*)(ws + 2101248 + 1048576);
    float* sum1 = rep12;            // [REP][64]
    float* sq1  = rep12 + REP*64;
    float* sum2 = rep12 + 2*REP*64;
    float* sq2  = rep12 + 3*REP*64;
    // conv3 stat replicas (64 KB) alias featT: featT is dead after conv1m.
    float* rep3 = (float*)featT;
    float* sum3 = rep3;             // [REP][128]
    float* sq3  = rep3 + REP*128;

    hipMemsetAsync(rep12, 0, 4*REP*64*sizeof(float), stream);

    k_feat<<<dim3(N_/64, B_), 256, 0, stream>>>(feat, featT);
    k_prep<<<(B_*N_)/256, 256, 0, stream>>>(loc, locP);
    k_knn<<<B_*M_, 256, 0, stream>>>(locP, nloc, idx);

    k_conv1m<<<NT/128, 256, 0, stream>>>(idx, loc, nloc, featT, W1, y1, sum1, sq1);
    k_fold<<<1, 128, 0, stream>>>(sum1, sq1, g1, b1, prm1, 64);
    // featT dead from here: zero conv3's replicas in its region
    hipMemsetAsync(rep3, 0, 2*REP*128*sizeof(float), stream);

    k_conv2m<<<NT/256, 256, 0, stream>>>(y1, W2, prm1, y2, sum2, sq2);
    k_fold<<<1, 128, 0, stream>>>(sum2, sq2, g2, b2, prm2, 64);

    k_conv3m<<<NT/256, 256, 0, stream>>>(y2, W3, prm2, sum3, sq3, gmax, gmin);
    k_fold<<<1, 128, 0, stream>>>(sum3, sq3, g3, b3, prm3, 128);

    k_final<<<dim3(B_*32), 256, 0, stream>>>(gmax, gmin, prm3, out);
}

// Round 11
// 366.991 us; speedup vs baseline: 1.0837x; 1.0058x over previous
//
#include <hip/hip_runtime.h>
#include <stdint.h>

// Problem constants
#define B_   16
#define N_   4096
#define M_   1024
#define NT   (B_*M_*32)      // 524288 samples
#define BM   (B_*M_)         // 16384 (b,m) groups
#define REP  64              // stats-accumulator replicas (atomic decontention)

typedef unsigned short u16;
typedef unsigned long long u64;
typedef __attribute__((ext_vector_type(8))) short short8;   // 8 bf16 (4 VGPRs)
typedef __attribute__((ext_vector_type(4))) float f32x4;    // MFMA C/D

union FragU { uint4 u; short8 s; };

__device__ __forceinline__ float bf2f(u16 u){
    return __uint_as_float(((unsigned int)u) << 16);
}
__device__ __forceinline__ u16 f2bf(float f){
    unsigned int u = __float_as_uint(f);
    return (u16)((u + 0x7FFFu + ((u >> 16) & 1u)) >> 16);
}

// ---------------------------------------------------------------------------
// features [B][64][N] f32 -> featT [B][N][64] f32
// ---------------------------------------------------------------------------
__global__ __launch_bounds__(256) void k_feat(const float* __restrict__ feat,
                                              float* __restrict__ featT){
    __shared__ float tile[64][65];
    int b  = blockIdx.y;
    int n0 = blockIdx.x * 64;
    for (int t = threadIdx.x; t < 4096; t += 256){
        int c = t >> 6, n = t & 63;
        tile[c][n] = feat[((size_t)(b*64 + c))*N_ + n0 + n];
    }
    __syncthreads();
    for (int t = threadIdx.x; t < 4096; t += 256){
        int n = t >> 6, c = t & 63;
        featT[((size_t)(b*N_) + n0 + n)*64 + c] = tile[c][n];
    }
}

// ---------------------------------------------------------------------------
// pack loc -> (x,y,z,x2): removes per-query recompute of x2 in k_knn and
// turns the point load into one aligned dwordx4.
// ---------------------------------------------------------------------------
__global__ __launch_bounds__(256) void k_prep(const float* __restrict__ locF,
                                              float4* __restrict__ locP){
    int i = blockIdx.x*256 + threadIdx.x;   // B_*N_ = 65536 points
    float lx = locF[(size_t)i*3+0], ly = locF[(size_t)i*3+1], lz = locF[(size_t)i*3+2];
    float x2 = __fadd_rn(__fadd_rn(__fmul_rn(lx,lx), __fmul_rn(ly,ly)), __fmul_rn(lz,lz));
    locP[i] = make_float4(lx, ly, lz, x2);
}

// ---------------------------------------------------------------------------
// exact KNN (32 smallest of 4096): value-domain linear bucket select.
// r5/r8 lockstep version — empirically a strong local optimum.
// LEDGER of failed restructures (do not re-attempt without new evidence):
//  - r7 raw-bit radix-256: top byte = sign+exponent -> all keys in 3-5
//    buckets -> LDS same-address atomic serialization (conflicts 5.35M->37M),
//    103->194 us. Bucket DISTRIBUTION, not ops/elem, governs cost.
//  - r9 wave-autonomous (per-wave top-32 + 128->32 merge): deleted barriers
//    but added 4x rank work + serial 128-iter merge loops; occupancy already
//    hides barrier idle (m114 wave-overlap). 114->129 us.
// ---------------------------------------------------------------------------
__global__ __launch_bounds__(256) void k_knn(const float4* __restrict__ locP,
                                             const float* __restrict__ nlocF,
                                             int* __restrict__ idxOut){
    const int tid  = threadIdx.x;
    const int lane = tid & 63, wv = tid >> 6;
    const int q    = blockIdx.x;
    const int b    = q >> 10, m = q & 1023;

    float qx = nlocF[(size_t)(b*M_ + m)*3 + 0];
    float qy = nlocF[(size_t)(b*M_ + m)*3 + 1];
    float qz = nlocF[(size_t)(b*M_ + m)*3 + 2];
    float y2 = __fadd_rn(__fadd_rn(__fmul_rn(qx,qx), __fmul_rn(qy,qy)), __fmul_rn(qz,qz));

    unsigned int key[16];
    const float4* lb = locP + (size_t)b*N_;
    #pragma unroll
    for (int i = 0; i < 16; ++i){
        int n = i*256 + tid;
        float4 p = lb[n];
        float dt = __fadd_rn(__fadd_rn(__fmul_rn(qx,p.x), __fmul_rn(qy,p.y)), __fmul_rn(qz,p.z));
        float d2 = __fsub_rn(__fadd_rn(y2, p.w), __fmul_rn(2.0f, dt));
        d2 = fmaxf(d2, 0.0f);
        key[i] = __float_as_uint(d2);
    }

    __shared__ unsigned int hist[4][256];
    __shared__ float wmm[4][2];
    __shared__ u64 cand[128];
    __shared__ int sOut[32];
    __shared__ int outCnt, candCnt;

    float lmin = 3.4e38f, lmax = 0.0f;
    #pragma unroll
    for (int i = 0; i < 16; ++i){
        float kf = __uint_as_float(key[i]);
        lmin = fminf(lmin, kf); lmax = fmaxf(lmax, kf);
    }
    #pragma unroll
    for (int st = 1; st < 64; st <<= 1){
        lmin = fminf(lmin, __shfl_xor(lmin, st, 64));
        lmax = fmaxf(lmax, __shfl_xor(lmax, st, 64));
    }
    if (tid == 0){ outCnt = 0; candCnt = 0; }
    if (lane == 0){ wmm[wv][0] = lmin; wmm[wv][1] = lmax; }
    __syncthreads();
    float lo = fminf(fminf(wmm[0][0], wmm[1][0]), fminf(wmm[2][0], wmm[3][0]));
    float hi = fmaxf(fmaxf(wmm[0][1], wmm[1][1]), fmaxf(wmm[2][1], wmm[3][1]));

    unsigned int act = 0xFFFFu;
    int bkt[16];
    int R = 32;

    for (int lvl = 0; lvl < 8; ++lvl){
        float scale = 255.0f / fmaxf(hi - lo, 1e-35f);
        ((uint4*)hist)[tid] = make_uint4(0,0,0,0);
        __syncthreads();
        #pragma unroll
        for (int i = 0; i < 16; ++i){
            if (act & (1u << i)){
                float kf = __uint_as_float(key[i]);
                int bb = (int)((kf - lo) * scale);
                bb = bb < 0 ? 0 : (bb > 255 ? 255 : bb);
                bkt[i] = bb;
                atomicAdd(&hist[wv][bb], 1u);
            }
        }
        __syncthreads();
        uint4 ha = *(const uint4*)&hist[0][lane << 2];
        uint4 hb = *(const uint4*)&hist[1][lane << 2];
        uint4 hc = *(const uint4*)&hist[2][lane << 2];
        uint4 hd = *(const uint4*)&hist[3][lane << 2];
        uint4 h = make_uint4(ha.x+hb.x+hc.x+hd.x, ha.y+hb.y+hc.y+hd.y,
                             ha.z+hb.z+hc.z+hd.z, ha.w+hb.w+hc.w+hd.w);
        int tot = (int)(h.x + h.y + h.z + h.w);
        int v = tot;
        #pragma unroll
        for (int st = 1; st < 64; st <<= 1){
            int u = __shfl_up(v, st, 64);
            if (lane >= st) v += u;
        }
        u64 bal = __ballot(v >= R);
        int Ls = __ffsll((unsigned long long)bal) - 1;
        int exclS = __shfl(v - tot, Ls, 64);
        int hx = __shfl((int)h.x, Ls, 64), hy = __shfl((int)h.y, Ls, 64);
        int hz = __shfl((int)h.z, Ls, 64), hw = __shfl((int)h.w, Ls, 64);
        int c0 = exclS + hx, c1 = c0 + hy, c2 = c1 + hz;
        int jj    = (c0 >= R) ? 0 : (c1 >= R) ? 1 : (c2 >= R) ? 2 : 3;
        int below = (jj == 0) ? exclS : (jj == 1) ? c0 : (jj == 2) ? c1 : c2;
        int cnt   = (jj == 0) ? hx : (jj == 1) ? hy : (jj == 2) ? hz : hw;
        int qb = Ls*4 + jj;
        R -= below;
        bool brk = (cnt <= 128) || (lvl == 7);

        float nlo = 3.4e38f, nhi = 0.0f;
        #pragma unroll
        for (int i = 0; i < 16; ++i){
            if (act & (1u << i)){
                int bb = bkt[i];
                if (bb < qb){
                    int pos = atomicAdd(&outCnt, 1);
                    if (pos < 32) sOut[pos] = i*256 + tid;
                    act &= ~(1u << i);
                } else if (bb > qb){
                    act &= ~(1u << i);
                } else if (!brk){
                    float kf = __uint_as_float(key[i]);
                    nlo = fminf(nlo, kf); nhi = fmaxf(nhi, kf);
                }
            }
        }
        if (brk) break;
        #pragma unroll
        for (int st = 1; st < 64; st <<= 1){
            nlo = fminf(nlo, __shfl_xor(nlo, st, 64));
            nhi = fmaxf(nhi, __shfl_xor(nhi, st, 64));
        }
        __syncthreads();
        if (lane == 0){ wmm[wv][0] = nlo; wmm[wv][1] = nhi; }
        __syncthreads();
        lo = fminf(fminf(wmm[0][0], wmm[1][0]), fminf(wmm[2][0], wmm[3][0]));
        hi = fmaxf(fmaxf(wmm[0][1], wmm[1][1]), fmaxf(wmm[2][1], wmm[3][1]));
    }

    #pragma unroll
    for (int i = 0; i < 16; ++i){
        if (act & (1u << i)){
            int pos = atomicAdd(&candCnt, 1);
            if (pos < 128) cand[pos] = (((u64)key[i]) << 32) | (unsigned int)(i*256 + tid);
        }
    }
    __syncthreads();
    int c = candCnt < 128 ? candCnt : 128;
    int base = outCnt;
    if (tid < c){
        u64 me = cand[tid];
        int rank = 0;
        for (int j = 0; j < c; ++j) rank += (cand[j] < me) ? 1 : 0;
        if (rank < R) sOut[base + rank] = (int)(me & 0xFFFFFFFFull);
    }
    __syncthreads();
    if (tid < 32) idxOut[(size_t)q*32 + tid] = sOut[tid];
}

// ---------------------------------------------------------------------------
// conv1 via MFMA, direct-to-register A gather; stats via replicated atomics.
// r11: tileT ALIASES bfB (bfB dead after MFMA loop; barrier inserted before
// the transpose writes). LDS 38.4 KB -> 21 KB => 4 -> 7 blocks/CU, to hide
// the random featT gather latency with TLP (r3 lesson: this kernel shape is
// latency-sensitive at low occupancy).
// ---------------------------------------------------------------------------
__global__ __launch_bounds__(256) void k_conv1m(const int* __restrict__ idx,
                                                const float* __restrict__ locF,
                                                const float* __restrict__ nlocF,
                                                const float* __restrict__ featT,
                                                const float* __restrict__ W1,
                                                u16* __restrict__ y1,
                                                float* __restrict__ gsum,
                                                float* __restrict__ gsq){
    __shared__ uint4 smemU[1280];   // 20 KB: bfB frags (nt*5+kk)*64 + lane
    uint4* bfB  = smemU;
    u16*  tileT = (u16*)smemU;      // 17 KB transpose-out (ALIAS; bfB dead by then)
    __shared__ float sSum[64], sSq[64];
    const int t   = threadIdx.x;
    const int bid = blockIdx.x;
    const int rep = bid & (REP-1);
    const int swz = (bid & 7)*512 + (bid >> 3);   // XCD-contiguous chunks
    const int s0  = swz * 128;
    const int b   = s0 >> 15;

    if (t < 64){ sSum[t] = 0.0f; sSq[t] = 0.0f; }

    // stage B': W1 hi duplicated in both halves of each k'-pair word
    #pragma unroll
    for (int rp = 0; rp < 5; ++rp){
        int cid = rp*256 + t;             // = (nt*5+kk)*64 + ln, cid < 1280
        int ln  = cid & 63;
        int kk  = (cid >> 6) % 5;
        int nt  = cid / 320;
        int o   = nt*16 + (ln & 15);
        int qq  = ln >> 4;
        int cb  = kk*16 + qq*4;           // phys channel base of this uint4
        unsigned int d[4];
        #pragma unroll
        for (int h = 0; h < 4; ++h){
            int c = cb + h;
            float wv = (c < 64) ? W1[o*67 + 3 + c] : ((c < 67) ? W1[o*67 + (c - 64)] : 0.0f);
            unsigned int wh = (unsigned int)f2bf(wv);
            d[h] = wh | (wh << 16);
        }
        bfB[cid] = make_uint4(d[0], d[1], d[2], d[3]);
    }

    // direct A gather: wave w -> m-tiles 2w,2w+1; lane q=l>>4 selects k-quad
    const int w = t >> 6, lane = t & 63;
    const int m15 = lane & 15, q = lane >> 4;

    int nrow[2], sg[2];
    float4 fa[2][4];
    #pragma unroll
    for (int mt = 0; mt < 2; ++mt){
        int sl = (2*w + mt)*16 + m15;
        sg[mt] = s0 + sl;
        int n = idx[sg[mt]]; if ((unsigned)n >= N_) n = 0;
        nrow[mt] = n;
        const float4* fp = (const float4*)&featT[((size_t)(b*N_) + n)*64];
        #pragma unroll
        for (int kq = 0; kq < 4; ++kq)
            fa[mt][kq] = fp[kq*4 + q];     // phys cols kq*16+q*4 .. +3
    }
    // xyz fragment (kk=4): only q==0 lanes carry data (phys c 64..67)
    uint4 axyz[2];
    axyz[0] = make_uint4(0,0,0,0); axyz[1] = make_uint4(0,0,0,0);
    if (q == 0){
        #pragma unroll
        for (int mt = 0; mt < 2; ++mt){
            int n = nrow[mt];
            int m = (sg[mt] >> 5) & 1023;
            const float* lp = &locF[(size_t)(b*N_ + n)*3];
            const float* qp = &nlocF[(size_t)(b*M_ + m)*3];
            unsigned int dd[3];
            #pragma unroll
            for (int e = 0; e < 3; ++e){
                float r  = lp[e] - qp[e];
                u16 hi   = f2bf(r);
                float lo = r - bf2f(hi);
                dd[e] = (unsigned int)hi | (((unsigned int)f2bf(lo)) << 16);
            }
            axyz[mt] = make_uint4(dd[0], dd[1], dd[2], 0u);
        }
    }
    __syncthreads();   // bfB ready (also covers sSum init)

    f32x4 acc[2][4];
    #pragma unroll
    for (int mt = 0; mt < 2; ++mt)
        #pragma unroll
        for (int nt = 0; nt < 4; ++nt)
            acc[mt][nt] = (f32x4){0.0f, 0.0f, 0.0f, 0.0f};

    #pragma unroll
    for (int kk = 0; kk < 5; ++kk){
        FragU af[2];
        #pragma unroll
        for (int mt = 0; mt < 2; ++mt){
            if (kk < 4){
                float4 f = fa[mt][kk];
                float fv[4] = {f.x, f.y, f.z, f.w};
                unsigned int d[4];
                #pragma unroll
                for (int e = 0; e < 4; ++e){
                    u16 hi   = f2bf(fv[e]);
                    float lo = fv[e] - bf2f(hi);
                    d[e] = (unsigned int)hi | (((unsigned int)f2bf(lo)) << 16);
                }
                af[mt].u = make_uint4(d[0], d[1], d[2], d[3]);
            } else {
                af[mt].u = axyz[mt];
            }
        }
        #pragma unroll
        for (int nt = 0; nt < 4; ++nt){
            FragU bu; bu.u = bfB[(nt*5 + kk)*64 + lane];
            #pragma unroll
            for (int mt = 0; mt < 2; ++mt)
                acc[mt][nt] = __builtin_amdgcn_mfma_f32_16x16x32_bf16(af[mt].s, bu.s, acc[mt][nt], 0, 0, 0);
        }
    }

    // fused stats: channel o = nt*16 + (lane&15); butterfly strides 16,32
    {
        float st4[4], sq4[4];
        #pragma unroll
        for (int nt = 0; nt < 4; ++nt){ st4[nt] = 0.0f; sq4[nt] = 0.0f; }
        #pragma unroll
        for (int mt = 0; mt < 2; ++mt)
            #pragma unroll
            for (int nt = 0; nt < 4; ++nt){
                f32x4 a = acc[mt][nt];
                st4[nt] += (a[0] + a[1]) + (a[2] + a[3]);
                float qv = a[0]*a[0];
                qv = fmaf(a[1], a[1], qv); qv = fmaf(a[2], a[2], qv); qv = fmaf(a[3], a[3], qv);
                sq4[nt] += qv;
            }
        #pragma unroll
        for (int st = 16; st < 64; st <<= 1){
            #pragma unroll
            for (int nt = 0; nt < 4; ++nt){
                st4[nt] += __shfl_xor(st4[nt], st, 64);
                sq4[nt] += __shfl_xor(sq4[nt], st, 64);
            }
        }
        if (lane < 16){
            #pragma unroll
            for (int nt = 0; nt < 4; ++nt){
                atomicAdd(&sSum[nt*16 + lane], st4[nt]);
                atomicAdd(&sSq[nt*16 + lane],  sq4[nt]);
            }
        }
    }
    __syncthreads();   // ALL waves done reading bfB before tileT overwrites it

    // transpose D -> channel-major bf16 via padded LDS tile (aliases bfB)
    #pragma unroll
    for (int mt = 0; mt < 2; ++mt){
        int s_base = w*32 + mt*16 + (lane >> 4)*4;
        #pragma unroll
        for (int nt = 0; nt < 4; ++nt){
            int o = nt*16 + (lane & 15);
            f32x4 a = acc[mt][nt];
            unsigned int p01 = (unsigned int)f2bf(a[0]) | (((unsigned int)f2bf(a[1])) << 16);
            unsigned int p23 = (unsigned int)f2bf(a[2]) | (((unsigned int)f2bf(a[3])) << 16);
            *(unsigned int*)&tileT[o*136 + s_base]     = p01;
            *(unsigned int*)&tileT[o*136 + s_base + 2] = p23;
        }
    }
    __syncthreads();

    // coalesced channel-major store: thread t -> channel c=t>>2, 32-sample chunk
    {
        int c  = t >> 2;
        int g0 = (t & 3)*32;
        #pragma unroll
        for (int j = 0; j < 4; ++j){
            uint4 v = *(const uint4*)&tileT[c*136 + g0 + j*8];
            *(uint4*)&y1[(size_t)c*NT + s0 + g0 + j*8] = v;
        }
    }
    if (t < 64){
        atomicAdd(&gsum[rep*64 + t], sSum[t]);
        atomicAdd(&gsq[rep*64 + t],  sSq[t]);
    }
}

// ---------------------------------------------------------------------------
// conv2 via MFMA: A = affine+relu(y1) frags (XOR-swizzled LDS), B = W2 frags;
// fused per-channel stats (replicated atomics). r11: tileT ALIASES bfA+bfB
// (both dead after the MFMA loop; barrier inserted before transpose writes).
// LDS 74 KB -> 41 KB => 2 -> 3 blocks/CU.
// ---------------------------------------------------------------------------
__global__ __launch_bounds__(256) void k_conv2m(const u16* __restrict__ yin,
                                                const float* __restrict__ W2,
                                                const float* __restrict__ prm,
                                                u16* __restrict__ yout,
                                                float* __restrict__ gsum,
                                                float* __restrict__ gsq){
    __shared__ uint4 smemU[2560];   // 40 KB: bfA [0,2048), bfB [2048,2560)
    uint4* bfA  = smemU;            // act frags: (mtg*2+kk)*64 + (l64 ^ (mtg&7))
    uint4* bfB  = smemU + 2048;     // W2 frags:  (nt*2+kk)*64 + lane
    u16*  tileT = (u16*)smemU;      // 33 KB transpose-out, stride 264 u16 (ALIAS)
    __shared__ float sS[64], sT[64];
    __shared__ float sSum[64], sSq[64];
    const int t   = threadIdx.x;
    const int rep = blockIdx.x & (REP-1);
    const int s0  = blockIdx.x * 256;

    if (t < 64){ sS[t] = prm[t]; sT[t] = prm[64 + t]; sSum[t] = 0.0f; sSq[t] = 0.0f; }
    __syncthreads();

    // stage B: W2 [64][64] f32 -> bf16 frags (n=o within tile), nt in [0,4)
    #pragma unroll
    for (int rp = 0; rp < 2; ++rp){
        int cid = rp*256 + t;
        int ln  = cid & 63;
        int kk  = (cid >> 6) & 1;
        int nt  = cid >> 7;
        int o   = nt*16 + (ln & 15);
        int k0  = kk*32 + (ln >> 4)*8;
        const float* wp = &W2[o*64 + k0];
        unsigned int d[4];
        #pragma unroll
        for (int h = 0; h < 4; ++h)
            d[h] = (unsigned int)f2bf(wp[2*h]) | (((unsigned int)f2bf(wp[2*h+1])) << 16);
        bfB[cid] = make_uint4(d[0], d[1], d[2], d[3]);
    }

    // stage A: y1 channel-major; affine+relu; m=sample frags, XOR-swizzled
    {
        int oct = t >> 5;            // channels oct*8..+7: kk=oct>>2, qd=oct&3
        int sg  = t & 31;            // samples sg*8..+7 (local)
        int c0  = oct*8;
        int kk  = oct >> 2;
        int qd  = oct & 3;
        u16 rb[8][8];                // [j (=c-c0)][i (=sample)] — constant-indexed only
        #pragma unroll
        for (int j = 0; j < 8; ++j){
            int c = c0 + j;
            uint4 pk = *(const uint4*)&yin[(size_t)c*NT + s0 + sg*8];
            float sc = sS[c], tb = sT[c];
            unsigned int w4[4] = {pk.x, pk.y, pk.z, pk.w};
            #pragma unroll
            for (int h = 0; h < 4; ++h){
                rb[j][2*h]   = f2bf(fmaxf(fmaf(bf2f((u16)(w4[h] & 0xFFFF)), sc, tb), 0.0f));
                rb[j][2*h+1] = f2bf(fmaxf(fmaf(bf2f((u16)(w4[h] >> 16)),   sc, tb), 0.0f));
            }
        }
        #pragma unroll
        for (int i = 0; i < 8; ++i){            // i is a literal after unroll
            int s   = sg*8 + i;
            int mtg = s >> 4, m15 = s & 15;
            int l64 = qd*16 + m15;
            int cb  = (mtg*2 + kk)*64 + (l64 ^ (mtg & 7));   // XOR swizzle
            unsigned int d[4];
            #pragma unroll
            for (int h = 0; h < 4; ++h)
                d[h] = (unsigned int)rb[2*h][i] | (((unsigned int)rb[2*h+1][i]) << 16);
            bfA[cb] = make_uint4(d[0], d[1], d[2], d[3]);
        }
    }
    __syncthreads();

    // MFMA: wave w -> m-tiles 4w..4w+3 (samples w*64..+63), 4 n-tiles (64 ch)
    const int w = t >> 6, lane = t & 63;
    f32x4 acc[4][4];
    #pragma unroll
    for (int mt = 0; mt < 4; ++mt)
        #pragma unroll
        for (int nt = 0; nt < 4; ++nt)
            acc[mt][nt] = (f32x4){0.0f, 0.0f, 0.0f, 0.0f};

    #pragma unroll
    for (int kk = 0; kk < 2; ++kk){
        short8 af[4];
        #pragma unroll
        for (int mt = 0; mt < 4; ++mt){
            int tile = 4*w + mt;
            af[mt] = *((const short8*)&bfA[(tile*2 + kk)*64 + (lane ^ (tile & 7))]);
        }
        #pragma unroll
        for (int nt = 0; nt < 4; ++nt){
            short8 bfr = *((const short8*)&bfB[(nt*2 + kk)*64 + lane]);
            #pragma unroll
            for (int mt = 0; mt < 4; ++mt)
                acc[mt][nt] = __builtin_amdgcn_mfma_f32_16x16x32_bf16(af[mt], bfr, acc[mt][nt], 0, 0, 0);
        }
    }

    // fused stats: channel o = nt*16 + (lane&15); butterfly strides 16,32
    {
        float st4[4], sq4[4];
        #pragma unroll
        for (int nt = 0; nt < 4; ++nt){ st4[nt] = 0.0f; sq4[nt] = 0.0f; }
        #pragma unroll
        for (int mt = 0; mt < 4; ++mt)
            #pragma unroll
            for (int nt = 0; nt < 4; ++nt){
                f32x4 a = acc[mt][nt];
                st4[nt] += (a[0] + a[1]) + (a[2] + a[3]);
                float qq = a[0]*a[0];
                qq = fmaf(a[1], a[1], qq); qq = fmaf(a[2], a[2], qq); qq = fmaf(a[3], a[3], qq);
                sq4[nt] += qq;
            }
        #pragma unroll
        for (int st = 16; st < 64; st <<= 1){
            #pragma unroll
            for (int nt = 0; nt < 4; ++nt){
                st4[nt] += __shfl_xor(st4[nt], st, 64);
                sq4[nt] += __shfl_xor(sq4[nt], st, 64);
            }
        }
        if (lane < 16){
            #pragma unroll
            for (int nt = 0; nt < 4; ++nt){
                atomicAdd(&sSum[nt*16 + lane], st4[nt]);
                atomicAdd(&sSq[nt*16 + lane],  sq4[nt]);
            }
        }
    }
    __syncthreads();   // ALL waves done reading bfA/bfB before tileT overwrites

    // transpose D -> channel-major bf16 via padded LDS tile (aliases bfA/bfB)
    #pragma unroll
    for (int mt = 0; mt < 4; ++mt){
        int s_base = w*64 + mt*16 + (lane >> 4)*4;
        #pragma unroll
        for (int nt = 0; nt < 4; ++nt){
            int o = nt*16 + (lane & 15);
            f32x4 a = acc[mt][nt];
            unsigned int p01 = (unsigned int)f2bf(a[0]) | (((unsigned int)f2bf(a[1])) << 16);
            unsigned int p23 = (unsigned int)f2bf(a[2]) | (((unsigned int)f2bf(a[3])) << 16);
            *(unsigned int*)&tileT[o*264 + s_base]     = p01;
            *(unsigned int*)&tileT[o*264 + s_base + 2] = p23;
        }
    }
    __syncthreads();

    // coalesced channel-major store: thread t -> row c=t>>2, 8x16B chunks
    {
        int c  = t >> 2;
        int g0 = (t & 3)*8;
        #pragma unroll
        for (int j = 0; j < 8; ++j){
            uint4 v = *(const uint4*)&tileT[c*264 + (g0 + j)*8];
            *(uint4*)&yout[(size_t)c*NT + s0 + (g0 + j)*8] = v;
        }
    }
    if (t < 64){
        atomicAdd(&gsum[rep*64 + t], sSum[t]);
        atomicAdd(&gsq[rep*64 + t],  sSq[t]);
    }
}

// ---------------------------------------------------------------------------
// conv3 via MFMA: A = activations (m=sample), B = W3 (n=channel) -> D row =
// sample. Epilogue: in-reg reduce + cross-quad butterfly; gmax/gmin
// [group][o] coalesced; stats via replicated atomics. (No tileT here; bfA and
// bfB both live through MFMA -> no alias opportunity. 49 KB -> 3 blocks/CU.)
// ---------------------------------------------------------------------------
__global__ __launch_bounds__(256) void k_conv3m(const u16* __restrict__ yin,
                                                const float* __restrict__ W3,
                                                const float* __restrict__ prm,
                                                float* __restrict__ gsum, float* __restrict__ gsq,
                                                float* __restrict__ gmax, float* __restrict__ gmin){
    __shared__ uint4 bfA[2048];     // act frags: (mtg*2+kk)*64 + (lane64 ^ (mtg&7))  (32 KB)
    __shared__ uint4 bfB[1024];     // W3 frags:  (nt*2+kk)*64 + lane                 (16 KB)
    __shared__ float sS[64], sT[64];
    __shared__ float sSum[128], sSq[128];
    const int t   = threadIdx.x;
    const int rep = blockIdx.x & (REP-1);
    const int s0  = blockIdx.x * 256;

    if (t < 64){ sS[t] = prm[t]; sT[t] = prm[64 + t]; }
    if (t < 128){ sSum[t] = 0.0f; sSq[t] = 0.0f; }
    __syncthreads();

    // stage B: W3 [128][64] f32 -> bf16 frags (n=channel within tile)
    #pragma unroll
    for (int rp = 0; rp < 4; ++rp){
        int cid = rp*256 + t;
        int ln  = cid & 63;
        int kk  = (cid >> 6) & 1;
        int nt  = cid >> 7;
        int o   = nt*16 + (ln & 15);
        int k0  = kk*32 + (ln >> 4)*8;
        const float* wp = &W3[o*64 + k0];
        unsigned int d[4];
        #pragma unroll
        for (int h = 0; h < 4; ++h)
            d[h] = (unsigned int)f2bf(wp[2*h]) | (((unsigned int)f2bf(wp[2*h+1])) << 16);
        bfB[cid] = make_uint4(d[0], d[1], d[2], d[3]);
    }

    // stage A: y2 channel-major; affine+relu; m=sample frags, XOR-swizzled
    {
        int oct = t >> 5;            // channels oct*8..+7: kk=oct>>2, qd=oct&3
        int sg  = t & 31;            // samples sg*8..+7 (local)
        int c0  = oct*8;
        int kk  = oct >> 2;
        int qd  = oct & 3;
        u16 rb[8][8];                // [j (=c-c0)][i (=sample)] — constant-indexed only
        #pragma unroll
        for (int j = 0; j < 8; ++j){
            int c = c0 + j;
            uint4 pk = *(const uint4*)&yin[(size_t)c*NT + s0 + sg*8];
            float sc = sS[c], tb = sT[c];
            unsigned int w4[4] = {pk.x, pk.y, pk.z, pk.w};
            #pragma unroll
            for (int h = 0; h < 4; ++h){
                rb[j][2*h]   = f2bf(fmaxf(fmaf(bf2f((u16)(w4[h] & 0xFFFF)), sc, tb), 0.0f));
                rb[j][2*h+1] = f2bf(fmaxf(fmaf(bf2f((u16)(w4[h] >> 16)),   sc, tb), 0.0f));
            }
        }
        #pragma unroll
        for (int i = 0; i < 8; ++i){            // i is a literal after unroll
            int s   = sg*8 + i;
            int mtg = s >> 4, m15 = s & 15;
            int l64 = qd*16 + m15;
            int cb  = (mtg*2 + kk)*64 + (l64 ^ (mtg & 7));   // XOR swizzle
            unsigned int d[4];
            #pragma unroll
            for (int h = 0; h < 4; ++h)
                d[h] = (unsigned int)rb[2*h][i] | (((unsigned int)rb[2*h+1][i]) << 16);
            bfA[cb] = make_uint4(d[0], d[1], d[2], d[3]);
        }
    }
    __syncthreads();

    // MFMA: wave w -> m-tiles 4w..4w+3 (samples w*64..+63), all 8 n-tiles
    const int w = t >> 6, lane = t & 63;
    f32x4 acc[4][8];
    #pragma unroll
    for (int mt = 0; mt < 4; ++mt)
        #pragma unroll
        for (int nt = 0; nt < 8; ++nt)
            acc[mt][nt] = (f32x4){0.0f, 0.0f, 0.0f, 0.0f};

    #pragma unroll
    for (int kk = 0; kk < 2; ++kk){
        short8 af[4];
        #pragma unroll
        for (int mt = 0; mt < 4; ++mt){
            int tile = 4*w + mt;
            af[mt] = *((const short8*)&bfA[(tile*2 + kk)*64 + (lane ^ (tile & 7))]);
        }
        #pragma unroll
        for (int nt = 0; nt < 8; ++nt){
            short8 bfr = *((const short8*)&bfB[(nt*2 + kk)*64 + lane]);
            #pragma unroll
            for (int mt = 0; mt < 4; ++mt)
                acc[mt][nt] = __builtin_amdgcn_mfma_f32_16x16x32_bf16(af[mt], bfr, acc[mt][nt], 0, 0, 0);
        }
    }

    // epilogue: group g (32 samples) = m-tiles (2g,2g+1). In-reg 8-value
    // reduce, then 2-stage cross-quad butterfly; quad0 writes coalesced rows.
    float stS[8], stQ[8];
    #pragma unroll
    for (int nt = 0; nt < 8; ++nt){ stS[nt] = 0.0f; stQ[nt] = 0.0f; }

    #pragma unroll
    for (int g = 0; g < 2; ++g){
        const size_t gg = (size_t)(blockIdx.x*8 + w*2 + g);
        #pragma unroll
        for (int nt = 0; nt < 8; ++nt){
            f32x4 a0 = acc[2*g][nt], a1 = acc[2*g+1][nt];
            float mx = fmaxf(fmaxf(fmaxf(a0[0], a0[1]), fmaxf(a0[2], a0[3])),
                             fmaxf(fmaxf(a1[0], a1[1]), fmaxf(a1[2], a1[3])));
            float mn = fminf(fminf(fminf(a0[0], a0[1]), fminf(a0[2], a0[3])),
                             fminf(fminf(a1[0], a1[1]), fminf(a1[2], a1[3])));
            float sm = (a0[0]+a0[1]) + (a0[2]+a0[3]) + (a1[0]+a1[1]) + (a1[2]+a1[3]);
            float sq = a0[0]*a0[0];
            sq = fmaf(a0[1], a0[1], sq); sq = fmaf(a0[2], a0[2], sq); sq = fmaf(a0[3], a0[3], sq);
            sq = fmaf(a1[0], a1[0], sq); sq = fmaf(a1[1], a1[1], sq); sq = fmaf(a1[2], a1[2], sq);
            sq = fmaf(a1[3], a1[3], sq);
            #pragma unroll
            for (int st = 16; st < 64; st <<= 1){
                mx = fmaxf(mx, __shfl_xor(mx, st, 64));
                mn = fminf(mn, __shfl_xor(mn, st, 64));
                sm += __shfl_xor(sm, st, 64);
                sq += __shfl_xor(sq, st, 64);
            }
            if (lane < 16){
                gmax[gg*128 + nt*16 + lane] = mx;
                gmin[gg*128 + nt*16 + lane] = mn;
            }
            stS[nt] += sm; stQ[nt] += sq;
        }
    }
    if (lane < 16){
        #pragma unroll
        for (int nt = 0; nt < 8; ++nt){
            atomicAdd(&sSum[nt*16 + lane], stS[nt]);
            atomicAdd(&sSq[nt*16 + lane],  stQ[nt]);
        }
    }
    __syncthreads();
    if (t < 128){
        atomicAdd(&gsum[rep*128 + t], sSum[t]);
        atomicAdd(&gsq[rep*128 + t],  sSq[t]);
    }
}

// fold BN into affine: reduce REP replicas, then s = g*rsqrt(var+eps),
// t = b - mu*s
__global__ void k_fold(const float* __restrict__ sum, const float* __restrict__ sumsq,
                       const float* __restrict__ gW, const float* __restrict__ bW,
                       float* __restrict__ prm, int C){
    int c = threadIdx.x;
    if (c < C){
        float s = 0.0f, q = 0.0f;
        for (int r = 0; r < REP; ++r){
            s += sum[r*C + c];
            q += sumsq[r*C + c];
        }
        const float inv = 1.0f / (float)NT;
        float mu  = s * inv;
        float var = q * inv - mu*mu;
        float sc  = gW[c] / sqrtf(var + 1e-5f);
        prm[c]     = sc;
        prm[C + c] = bW[c] - mu*sc;
    }
}

// ---------------------------------------------------------------------------
// out[b][o][m] = ReLU(s * (s>=0 ? gmax : gmin) + t); LDS-transpose version —
// reads coalesce over o (512B rows), writes coalesce over m. Tile stride 129
// -> conflict-free both sides.
// ---------------------------------------------------------------------------
__global__ __launch_bounds__(256) void k_final(const float* __restrict__ gmax,
                                               const float* __restrict__ gmin,
                                               const float* __restrict__ prm,
                                               float* __restrict__ out){
    __shared__ float tile[32][129];
    __shared__ float sS[128], sT[128];
    const int t   = threadIdx.x;
    const int blk = blockIdx.x;          // 512 blocks: b = blk>>5, mchunk = blk&31
    const int b   = blk >> 5;
    const int m0  = (blk & 31) * 32;
    if (t < 128){ sS[t] = prm[t]; sT[t] = prm[128 + t]; }
    __syncthreads();
    #pragma unroll
    for (int i = 0; i < 16; ++i){
        int v  = i*256 + t;
        int ml = v >> 7, o = v & 127;
        float sc = sS[o];
        size_t gi = (size_t)(b*M_ + m0 + ml)*128 + o;
        float val = (sc >= 0.0f) ? gmax[gi] : gmin[gi];
        tile[ml][o] = fmaxf(fmaf(val, sc, sT[o]), 0.0f);
    }
    __syncthreads();
    #pragma unroll
    for (int i = 0; i < 16; ++i){
        int v  = i*256 + t;
        int o  = v >> 5, ml = v & 31;
        out[((size_t)(b*128 + o))*M_ + m0 + ml] = tile[ml][o];
    }
}

// ---------------------------------------------------------------------------
extern "C" void kernel_launch(void* const* d_in, const int* in_sizes, int n_in,
                              void* d_out, int out_size, void* d_ws, size_t ws_size,
                              hipStream_t stream){
    const float* loc  = (const float*)d_in[0];
    const float* nloc = (const float*)d_in[1];
    const float* feat = (const float*)d_in[2];
    const float* W1   = (const float*)d_in[3];
    const float* g1   = (const float*)d_in[4];
    const float* b1   = (const float*)d_in[5];
    const float* W2   = (const float*)d_in[6];
    const float* g2   = (const float*)d_in[7];
    const float* b2   = (const float*)d_in[8];
    const float* W3   = (const float*)d_in[9];
    const float* g3   = (const float*)d_in[10];
    const float* b3   = (const float*)d_in[11];
    float* out = (float*)d_out;

    char* ws = (char*)d_ws;
    float* prm1  = (float*)(ws + 2048);              // 128 f
    float* prm2  = (float*)(ws + 2048 + 512);        // 128 f
    float* prm3  = (float*)(ws + 2048 + 1024);       // 256 f -> ends 4096
    int*   idx   = (int*)(ws + 4096);                // 2 MB
    float* gmax  = (float*)(ws + 2101248);           // 8 MB [BM][128]
    float* gmin  = (float*)(ws + 10489856);          // 8 MB
    float* featT = (float*)(ws + 18878464);          // 16 MB [B][N][64]
    u16*   y1    = (u16*)(ws + 35655680);            // 64 MB [64][NT]
    u16*   y2    = (u16*)(ws + 102764544);           // 64 MB  (ws >= 170 MB proven)
    // locP (1 MB) aliases gmax[0..1MB): dead before conv3m writes gmax.
    float4* locP = (float4*)gmax;
    // conv1/conv2 stat replicas (64 KB) alias gmax[1MB..1MB+64KB): read by
    // fold1/fold2, both stream-ordered before conv3m's first gmax write.
    float* rep12 = (float*)(ws + 2101248 + 1048576);
    float* sum1 = rep12;            // [REP][64]
    float* sq1  = rep12 + REP*64;
    float* sum2 = rep12 + 2*REP*64;
    float* sq2  = rep12 + 3*REP*64;
    // conv3 stat replicas (64 KB) alias featT: featT is dead after conv1m.
    float* rep3 = (float*)featT;
    float* sum3 = rep3;             // [REP][128]
    float* sq3  = rep3 + REP*128;

    hipMemsetAsync(rep12, 0, 4*REP*64*sizeof(float), stream);

    k_feat<<<dim3(N_/64, B_), 256, 0, stream>>>(feat, featT);
    k_prep<<<(B_*N_)/256, 256, 0, stream>>>(loc, locP);
    k_knn<<<B_*M_, 256, 0, stream>>>(locP, nloc, idx);

    k_conv1m<<<NT/128, 256, 0, stream>>>(idx, loc, nloc, featT, W1, y1, sum1, sq1);
    k_fold<<<1, 128, 0, stream>>>(sum1, sq1, g1, b1, prm1, 64);
    // featT dead from here: zero conv3's replicas in its region
    hipMemsetAsync(rep3, 0, 2*REP*128*sizeof(float), stream);

    k_conv2m<<<NT/256, 256, 0, stream>>>(y1, W2, prm1, y2, sum2, sq2);
    k_fold<<<1, 128, 0, stream>>>(sum2, sq2, g2, b2, prm2, 64);

    k_conv3m<<<NT/256, 256, 0, stream>>>(y2, W3, prm2, sum3, sq3, gmax, gmin);
    k_fold<<<1, 128, 0, stream>>>(sum3, sq3, g3, b3, prm3, 128);

    k_final<<<dim3(B_*32), 256, 0, stream>>>(gmax, gmin, prm3, out);
}